// Round 10
// baseline (357.249 us; speedup 1.0000x reference)
//
#include <hip/hip_runtime.h>
#include <math.h>

// ---------------------------------------------------------------------------
// SimGNN forward on MI355X — R23 best (336.3 us) + agg64 graph x feature split.
// R23 WIN: packed-bkt (uint32) CSR build, 345.4 -> 336.3.
// R24: agg64 is ~110 us aggregate (2 x ~55, by budget subtraction) — largest
// cost. Its gather set is xs = 6.4 MB/graph > 4 MB per-XCD L2 even with the
// parity split (same regime agg32 was in pre-R17). Split blockIdx into
// (graph, feature-half): g=bid&1, fh=(bid>>1)&1, quarter-wave per node-half.
// Each (g,fh) pins to 2 XCDs with a 3.2 MB < 4 MB working set — full L2 fit.
// Numerically identical (per-feature accumulation order unchanged).
// R22 WIN: agg64 parity split (−3.1). R20: HG=1024 regressed at const FETCH —
// agg32 is L2 queue-bound; HG=512 SETTLED (R14+R20). R17 WIN: agg32 parity
// split, FETCH 54.8->19.2 MB. R16 WIN: countB+scans fused into fillC.
// R15: scattered global atomics dead (50 MB coherence traffic).
// Pipeline: bcount/bscan/bwrite -> fillC_fused(row_ptr,dinv,col)
//   -> scale0/packW -> agg64 -> mfma1 -> agg64 -> mfma2 -> agg32_colsum
//   -> pool(ctx recomputed per block) -> ntn
// ---------------------------------------------------------------------------

#define NSLICE 64
#define NBLK   256

typedef _Float16 f16x8 __attribute__((ext_vector_type(8)));
typedef _Float16 f16x4 __attribute__((ext_vector_type(4)));
typedef _Float16 f16x2 __attribute__((ext_vector_type(2)));
typedef float    f32x4 __attribute__((ext_vector_type(4)));

// ---- bucket phase A: per-block slice counts (R12 exact) ----
__global__ void bcount_kernel(const int* __restrict__ ei1, const int* __restrict__ ei2,
                              int E, int N, int* __restrict__ gcnt, int chunk, int nsb) {
    __shared__ int cnt[NSLICE];
    int t = threadIdx.x;
    if (t < NSLICE) cnt[t] = 0;
    __syncthreads();
    int E2 = 2 * E;
    int lo = blockIdx.x * chunk;
    int hi = lo + chunk; if (hi > E2) hi = E2;
    for (int i = lo + t; i < hi; i += blockDim.x) {
        int dst = (i < E) ? ei1[E + i] : (ei2[E + (i - E)] + N);
        atomicAdd(&cnt[dst >> nsb], 1);
    }
    __syncthreads();
    if (t < NSLICE) gcnt[t * NBLK + blockIdx.x] = cnt[t];
}

// ---- bucket phase B: exclusive scan of gcnt[64*NBLK]; also row_ptr[M]=E2 ----
__global__ void bscan_kernel(int* __restrict__ gcnt, int* __restrict__ sliceStart,
                             int* __restrict__ row_ptr, int M, int E2) {
    __shared__ int sh[1024];
    int t = threadIdx.x;
    const int PER = (NSLICE * NBLK) / 1024;
    int base = t * PER;
    int vals[PER];
    int s = 0;
    #pragma unroll
    for (int k = 0; k < PER; ++k) { vals[k] = gcnt[base + k]; s += vals[k]; }
    sh[t] = s;
    __syncthreads();
    for (int off = 1; off < 1024; off <<= 1) {
        int v = (t >= off) ? sh[t - off] : 0;
        __syncthreads();
        sh[t] += v;
        __syncthreads();
    }
    int run = (t == 0) ? 0 : sh[t - 1];
    #pragma unroll
    for (int k = 0; k < PER; ++k) {
        gcnt[base + k] = run;
        run += vals[k];
    }
    __syncthreads();
    if (t < NSLICE) sliceStart[t] = gcnt[t * NBLK];
    if (t == 0) { sliceStart[NSLICE] = E2; row_ptr[M] = E2; }
}

// ---- bucket phase C: place edges (R23: packed uint32) ----
// w = (src << nsb) | (dst & (2^nsb - 1)); src < 2^(32-nsb) required
// (M = 100K < 2^17 <= 2^21 at nsb=11 — holds with huge margin).
__global__ void bwrite_kernel(const int* __restrict__ ei1, const int* __restrict__ ei2,
                              int E, int N, const int* __restrict__ gcnt,
                              unsigned* __restrict__ bkt, int chunk, int nsb) {
    __shared__ int cur[NSLICE];
    int t = threadIdx.x;
    if (t < NSLICE) cur[t] = gcnt[t * NBLK + blockIdx.x];
    __syncthreads();
    int E2 = 2 * E;
    unsigned mask = (1u << nsb) - 1u;
    int lo = blockIdx.x * chunk;
    int hi = lo + chunk; if (hi > E2) hi = E2;
    for (int i = lo + t; i < hi; i += blockDim.x) {
        int src, dst;
        if (i < E) { src = ei1[i];         dst = ei1[E + i]; }
        else       { src = ei2[i - E] + N; dst = ei2[E + (i - E)] + N; }
        int p = atomicAdd(&cur[dst >> nsb], 1);
        bkt[p] = ((unsigned)src << nsb) | ((unsigned)dst & mask);
    }
}

// ---- fillC_fused: one block per slice. Phase 1: LDS histogram of the
// slice's dsts (low nsb bits of packed word). Phase 2: LDS block-scan ->
// row_ptr/dinv (global base = sliceStart[slice]). Phase 3: place col via
// LDS cursors (hold global positions). No global atomics.
__global__ void fillC_fused_kernel(const unsigned* __restrict__ bkt,
                                   const int* __restrict__ sliceStart,
                                   int* __restrict__ row_ptr, float* __restrict__ dinv,
                                   int* __restrict__ col, int M, int nsb) {
    extern __shared__ int sm[];           // [nbins] hist/cursor + [1024] scan
    int nbins = 1 << nsb;
    unsigned mask = (unsigned)nbins - 1u;
    int* hist = sm;
    int* ssum = sm + nbins;
    int slice = blockIdx.x;
    int lo = slice << nsb;
    int t = threadIdx.x;                  // blockDim.x == 1024
    for (int j = t; j < nbins; j += 1024) hist[j] = 0;
    __syncthreads();
    int s = sliceStart[slice], e = sliceStart[slice + 1];
    // Phase 1: histogram over low bits
    for (int i = s + t; i < e; i += 1024)
        atomicAdd(&hist[bkt[i] & mask], 1);
    __syncthreads();
    // Phase 2: exclusive scan over nbins (PER bins per thread)
    const int PER = nbins >> 10;          // nbins/1024 (2 for nsb=11)
    int base = t * PER;
    int vals[4];                          // supports nsb up to 12
    int acc = 0;
    for (int k = 0; k < PER; ++k) { vals[k] = hist[base + k]; acc += vals[k]; }
    ssum[t] = acc;
    __syncthreads();
    for (int off = 1; off < 1024; off <<= 1) {
        int v = (t >= off) ? ssum[t - off] : 0;
        __syncthreads();
        ssum[t] += v;
        __syncthreads();
    }
    int run = s + ((t == 0) ? 0 : ssum[t - 1]);
    for (int k = 0; k < PER; ++k) {
        int idx = lo + base + k;
        if (idx < M) {
            row_ptr[idx] = run;
            dinv[idx] = rsqrtf((float)(vals[k] + 1));
        }
        hist[base + k] = run;             // becomes the global write cursor
        run += vals[k];
    }
    __syncthreads();
    // Phase 3: place edges (src = high bits)
    for (int i = s + t; i < e; i += 1024) {
        unsigned w = bkt[i];
        int p = atomicAdd(&hist[w & mask], 1);
        col[p] = (int)(w >> nsb);
    }
}

// xs0[i] = f16(x0[i] * dinv[i/64]); 4 elements per thread.
__global__ void scale0_kernel(const float* __restrict__ f1, const float* __restrict__ f2,
                              const float* __restrict__ dinv, _Float16* __restrict__ xs,
                              int n /* = N*64 */) {
    int i4 = (blockIdx.x * blockDim.x + threadIdx.x) * 4;
    if (i4 >= 2 * n) return;
    const float* src = (i4 < n) ? (f1 + i4) : (f2 + (i4 - n));
    float dv = dinv[i4 >> 6];
    float4 v = *(const float4*)src;
    f16x4 o = { (_Float16)(v.x * dv), (_Float16)(v.y * dv),
                (_Float16)(v.z * dv), (_Float16)(v.w * dv) };
    *(f16x4*)(xs + i4) = o;
}

// Pack W1,W2 (64x64) and W3 (64x32) into MFMA B-fragment order, f16.
__global__ void packW_kernel(const float* __restrict__ W1, const float* __restrict__ W2,
                             const float* __restrict__ W3, _Float16* __restrict__ pk) {
    int t = blockIdx.x * blockDim.x + threadIdx.x;
    if (t < 8192) {
        const float* W = (t < 4096) ? W1 : W2;
        int idx = t & 4095;
        int j = idx & 7, slot = idx >> 3;
        int lane = slot & 63, s = (slot >> 6) & 1, ct = slot >> 7;
        int k = s * 32 + ((lane >> 4) << 3) + j;
        int n = ct * 16 + (lane & 15);
        pk[t] = (_Float16)W[k * 64 + n];
    } else if (t < 10240) {
        int idx = t - 8192;
        int j = idx & 7, slot = idx >> 3;
        int lane = slot & 63, s = (slot >> 6) & 1, ct = slot >> 7;
        int k = s * 32 + ((lane >> 4) << 3) + j;
        int n = ct * 16 + (lane & 15);
        pk[t] = (_Float16)W3[k * 32 + n];
    }
}

// R24: quarter-wave per (node, feature-half). g=bid&1, fh=(bid>>1)&1 —
// each (graph, feature-half) pins to 2 XCDs; gather working set
// N*32*2B = 3.2 MB < 4 MB per-XCD L2 (full fit; was 6.4 MB at parity-only).
// 16 lanes x f16x2 = 64B per row-half. Numerically identical to fused form.
__global__ void agg64_kernel(const _Float16* __restrict__ xs, _Float16* __restrict__ out,
                             const int* __restrict__ row_ptr, const int* __restrict__ col,
                             const float* __restrict__ dinv, int N) {
    int g  = blockIdx.x & 1;
    int fh = (blockIdx.x >> 1) & 1;
    int nv = ((blockIdx.x >> 2) * blockDim.x + threadIdx.x) >> 4;
    int l = threadIdx.x & 15;
    if (nv >= N) return;
    int v = g * N + nv;
    size_t fo = (size_t)fh * 32;
    const f16x2* row = (const f16x2*)(xs + (size_t)v * 64 + fo);
    f16x2 sv = row[l];
    float ax = (float)sv.x, ay = (float)sv.y;
    int s = row_ptr[v], e = row_ptr[v + 1];
    int i = s;
    for (; i + 8 <= e; i += 8) {
        int u0 = col[i],     u1 = col[i + 1], u2 = col[i + 2], u3 = col[i + 3];
        int u4 = col[i + 4], u5 = col[i + 5], u6 = col[i + 6], u7 = col[i + 7];
        f16x2 p0 = ((const f16x2*)(xs + (size_t)u0 * 64 + fo))[l];
        f16x2 p1 = ((const f16x2*)(xs + (size_t)u1 * 64 + fo))[l];
        f16x2 p2 = ((const f16x2*)(xs + (size_t)u2 * 64 + fo))[l];
        f16x2 p3 = ((const f16x2*)(xs + (size_t)u3 * 64 + fo))[l];
        f16x2 p4 = ((const f16x2*)(xs + (size_t)u4 * 64 + fo))[l];
        f16x2 p5 = ((const f16x2*)(xs + (size_t)u5 * 64 + fo))[l];
        f16x2 p6 = ((const f16x2*)(xs + (size_t)u6 * 64 + fo))[l];
        f16x2 p7 = ((const f16x2*)(xs + (size_t)u7 * 64 + fo))[l];
        ax += (((float)p0.x + (float)p1.x) + ((float)p2.x + (float)p3.x))
            + (((float)p4.x + (float)p5.x) + ((float)p6.x + (float)p7.x));
        ay += (((float)p0.y + (float)p1.y) + ((float)p2.y + (float)p3.y))
            + (((float)p4.y + (float)p5.y) + ((float)p6.y + (float)p7.y));
    }
    for (; i + 4 <= e; i += 4) {
        int u0 = col[i], u1 = col[i + 1], u2 = col[i + 2], u3 = col[i + 3];
        f16x2 p0 = ((const f16x2*)(xs + (size_t)u0 * 64 + fo))[l];
        f16x2 p1 = ((const f16x2*)(xs + (size_t)u1 * 64 + fo))[l];
        f16x2 p2 = ((const f16x2*)(xs + (size_t)u2 * 64 + fo))[l];
        f16x2 p3 = ((const f16x2*)(xs + (size_t)u3 * 64 + fo))[l];
        ax += ((float)p0.x + (float)p1.x) + ((float)p2.x + (float)p3.x);
        ay += ((float)p0.y + (float)p1.y) + ((float)p2.y + (float)p3.y);
    }
    for (; i < e; ++i) {
        f16x2 p = ((const f16x2*)(xs + (size_t)col[i] * 64 + fo))[l];
        ax += (float)p.x; ay += (float)p.y;
    }
    float dv = dinv[v];
    f16x2 o = { (_Float16)(ax * dv), (_Float16)(ay * dv) };
    ((f16x2*)(out + (size_t)v * 64 + fo))[l] = o;
}

// MFMA GEMM: xs1 = f16(relu(t@W1+b1)*dinv). Wave = 16 rows x 64 cols, K=64.
__global__ void mfma_gemm64_kernel(const _Float16* __restrict__ tA, _Float16* __restrict__ out,
                                   const _Float16* __restrict__ pk, const float* __restrict__ b1,
                                   const float* __restrict__ dinv, int M) {
    int wave = (blockIdx.x * blockDim.x + threadIdx.x) >> 6;
    int lane = threadIdx.x & 63;
    int base = wave * 16;
    if (base >= M) return;
    int l15 = lane & 15, q = lane >> 4;
    const f16x8* arow = (const f16x8*)(tA + (size_t)(base + l15) * 64);
    f16x8 a0 = arow[q];
    f16x8 a1 = arow[q + 4];
    const f16x8* bp = (const f16x8*)pk;
    f32x4 acc[4];
    #pragma unroll
    for (int ct = 0; ct < 4; ++ct) {
        f32x4 c = {0.f, 0.f, 0.f, 0.f};
        c = __builtin_amdgcn_mfma_f32_16x16x32_f16(a0, bp[(ct * 2 + 0) * 64 + lane], c, 0, 0, 0);
        c = __builtin_amdgcn_mfma_f32_16x16x32_f16(a1, bp[(ct * 2 + 1) * 64 + lane], c, 0, 0, 0);
        acc[ct] = c;
    }
    float dv[4];
    #pragma unroll
    for (int r = 0; r < 4; ++r) dv[r] = dinv[base + q * 4 + r];
    #pragma unroll
    for (int ct = 0; ct < 4; ++ct) {
        float bj = b1[ct * 16 + l15];
        #pragma unroll
        for (int r = 0; r < 4; ++r)
            out[(size_t)(base + q * 4 + r) * 64 + ct * 16 + l15] =
                (_Float16)(fmaxf(acc[ct][r] + bj, 0.f) * dv[r]);
    }
}

// MFMA double GEMM: h3s = f16((relu(t@W2+b2)@W3)*dinv). LDS transpose between.
__global__ void mfma_gemm64_32_kernel(const _Float16* __restrict__ tA, _Float16* __restrict__ out,
                                      const _Float16* __restrict__ pk2, const _Float16* __restrict__ pk3,
                                      const float* __restrict__ b2, const float* __restrict__ dinv,
                                      int M) {
    __shared__ _Float16 xl[4][16][72];
    int wv = threadIdx.x >> 6;
    int wave = (blockIdx.x * blockDim.x + threadIdx.x) >> 6;
    int lane = threadIdx.x & 63;
    int base = wave * 16;
    if (base >= M) return;
    int l15 = lane & 15, q = lane >> 4;
    const f16x8* arow = (const f16x8*)(tA + (size_t)(base + l15) * 64);
    f16x8 a0 = arow[q];
    f16x8 a1 = arow[q + 4];
    const f16x8* bp2 = (const f16x8*)pk2;
    #pragma unroll
    for (int ct = 0; ct < 4; ++ct) {
        f32x4 c = {0.f, 0.f, 0.f, 0.f};
        c = __builtin_amdgcn_mfma_f32_16x16x32_f16(a0, bp2[(ct * 2 + 0) * 64 + lane], c, 0, 0, 0);
        c = __builtin_amdgcn_mfma_f32_16x16x32_f16(a1, bp2[(ct * 2 + 1) * 64 + lane], c, 0, 0, 0);
        float bj = b2[ct * 16 + l15];
        #pragma unroll
        for (int r = 0; r < 4; ++r)
            xl[wv][q * 4 + r][ct * 16 + l15] = (_Float16)fmaxf(c[r] + bj, 0.f);
    }
    const f16x8* xr = (const f16x8*)(&xl[wv][l15][0]);
    f16x8 e0 = xr[q];
    f16x8 e1 = xr[q + 4];
    const f16x8* bp3 = (const f16x8*)pk3;
    float dv[4];
    #pragma unroll
    for (int r = 0; r < 4; ++r) dv[r] = dinv[base + q * 4 + r];
    #pragma unroll
    for (int ct = 0; ct < 2; ++ct) {
        f32x4 c = {0.f, 0.f, 0.f, 0.f};
        c = __builtin_amdgcn_mfma_f32_16x16x32_f16(e0, bp3[(ct * 2 + 0) * 64 + lane], c, 0, 0, 0);
        c = __builtin_amdgcn_mfma_f32_16x16x32_f16(e1, bp3[(ct * 2 + 1) * 64 + lane], c, 0, 0, 0);
        #pragma unroll
        for (int r = 0; r < 4; ++r)
            out[(size_t)(base + q * 4 + r) * 32 + ct * 16 + l15] = (_Float16)(c[r] * dv[r]);
    }
}

// agg32: quarter-wave per node; a3 f32 out; fused colsums.
// R17: g = blockIdx&1 — parity split: per-XCD gather set 3.2 MB < 4 MB L2
// (FETCH 54.8->19.2 MB). HG=512 SETTLED (R14 + R20: x2 regresses in both
// thrash and L2-fit regimes — L2 queue-bound, not wave-starved).
__global__ void agg32_colsum_kernel(const _Float16* __restrict__ hs, float* __restrict__ out,
                                    const int* __restrict__ row_ptr, const int* __restrict__ col,
                                    const float* __restrict__ dinv, const float* __restrict__ b,
                                    float* __restrict__ msum, int N, int halfgrid) {
    int g = blockIdx.x & 1;
    int bid = blockIdx.x >> 1;
    int t = threadIdx.x;
    int l = t & 15;
    int qw = (bid * blockDim.x + t) >> 4;
    int nqw = (halfgrid * blockDim.x) >> 4;
    float blx = b[2 * l], bly = b[2 * l + 1];
    float csx = 0.f, csy = 0.f;
    int base = g * N;
    for (int vv = qw; vv < N; vv += nqw) {
        int v = base + vv;
        f16x2 sv = ((const f16x2*)(hs + (size_t)v * 32))[l];
        float ax = (float)sv.x, ay = (float)sv.y;
        int s = row_ptr[v], e = row_ptr[v + 1];
        int i = s;
        for (; i + 8 <= e; i += 8) {
            int u0 = col[i],     u1 = col[i + 1], u2 = col[i + 2], u3 = col[i + 3];
            int u4 = col[i + 4], u5 = col[i + 5], u6 = col[i + 6], u7 = col[i + 7];
            f16x2 p0 = ((const f16x2*)(hs + (size_t)u0 * 32))[l];
            f16x2 p1 = ((const f16x2*)(hs + (size_t)u1 * 32))[l];
            f16x2 p2 = ((const f16x2*)(hs + (size_t)u2 * 32))[l];
            f16x2 p3 = ((const f16x2*)(hs + (size_t)u3 * 32))[l];
            f16x2 p4 = ((const f16x2*)(hs + (size_t)u4 * 32))[l];
            f16x2 p5 = ((const f16x2*)(hs + (size_t)u5 * 32))[l];
            f16x2 p6 = ((const f16x2*)(hs + (size_t)u6 * 32))[l];
            f16x2 p7 = ((const f16x2*)(hs + (size_t)u7 * 32))[l];
            ax += (((float)p0.x + (float)p1.x) + ((float)p2.x + (float)p3.x))
                + (((float)p4.x + (float)p5.x) + ((float)p6.x + (float)p7.x));
            ay += (((float)p0.y + (float)p1.y) + ((float)p2.y + (float)p3.y))
                + (((float)p4.y + (float)p5.y) + ((float)p6.y + (float)p7.y));
        }
        for (; i + 4 <= e; i += 4) {
            int u0 = col[i], u1 = col[i + 1], u2 = col[i + 2], u3 = col[i + 3];
            f16x2 p0 = ((const f16x2*)(hs + (size_t)u0 * 32))[l];
            f16x2 p1 = ((const f16x2*)(hs + (size_t)u1 * 32))[l];
            f16x2 p2 = ((const f16x2*)(hs + (size_t)u2 * 32))[l];
            f16x2 p3 = ((const f16x2*)(hs + (size_t)u3 * 32))[l];
            ax += ((float)p0.x + (float)p1.x) + ((float)p2.x + (float)p3.x);
            ay += ((float)p0.y + (float)p1.y) + ((float)p2.y + (float)p3.y);
        }
        for (; i < e; ++i) {
            f16x2 p = ((const f16x2*)(hs + (size_t)col[i] * 32))[l];
            ax += (float)p.x; ay += (float)p.y;
        }
        float dv = dinv[v];
        float ox = ax * dv + blx, oy = ay * dv + bly;
        *(float2*)(out + (size_t)v * 32 + 2 * l) = make_float2(ox, oy);
        csx += ox; csy += oy;
    }
    __shared__ float spx[256], spy[256];
    spx[t] = csx; spy[t] = csy;
    __syncthreads();
    if (t < 16) {
        float sx = 0.f, sy = 0.f;
        for (int w = 0; w < 16; ++w) { sx += spx[w * 16 + t]; sy += spy[w * 16 + t]; }
        atomicAdd(&msum[g * 32 + 2 * t], sx);
        atomicAdd(&msum[g * 32 + 2 * t + 1], sy);
    }
}

// pool with ctx recomputed per block (ctx2 kernel fused away):
// ctx[j] = tanh(sum_i (msum[i]/N) * W_att[i][j]) — 1K FLOPs per block.
__global__ void pool2_kernel(const float* __restrict__ a3, const float* __restrict__ msum,
                             const float* __restrict__ W_att, float* __restrict__ pooled,
                             int N, int halfgrid) {
    int g = (blockIdx.x >= halfgrid) ? 1 : 0;
    int bid = blockIdx.x - g * halfgrid;
    int t = threadIdx.x;
    int j = t & 31;
    float invN = 1.f / (float)N;
    float acc = 0.f;
    for (int i = 0; i < 32; ++i) acc += (msum[g * 32 + i] * invN) * W_att[i * 32 + j];
    float cj = tanhf(acc);
    int hw = (bid * blockDim.x + t) >> 5;
    int nhw = (halfgrid * blockDim.x) >> 5;
    const float* base = a3 + (size_t)g * N * 32;
    float local = 0.f;
    for (int n = hw; n < N; n += nhw) {
        float v = base[(size_t)n * 32 + j];
        float d = v * cj;
        #pragma unroll
        for (int off = 16; off; off >>= 1) d += __shfl_xor(d, off);
        float s = 1.f / (1.f + __expf(-d));
        local += s * v;
    }
    __shared__ float sp[256];
    sp[t] = local;
    __syncthreads();
    if (t < 32) {
        float s = 0.f;
        for (int w = 0; w < 8; ++w) s += sp[w * 32 + t];
        atomicAdd(&pooled[g * 32 + t], s);
    }
}

__global__ void ntn_kernel(const float* __restrict__ p1, const float* __restrict__ p2,
                           const float* __restrict__ W_tn, const float* __restrict__ W_block,
                           const float* __restrict__ b_tn, float* __restrict__ out) {
    int k = threadIdx.x;
    if (k >= 16) return;
    float sc = 0.f;
    for (int i = 0; i < 32; ++i) {
        float e1 = p1[i];
        for (int j = 0; j < 32; ++j) sc += e1 * W_tn[i * 512 + j * 16 + k] * p2[j];
    }
    float bl = 0.f;
    for (int j = 0; j < 32; ++j)
        bl += W_block[k * 64 + j] * p1[j] + W_block[k * 64 + 32 + j] * p2[j];
    float v = sc + bl + b_tn[k];
    out[k] = v > 0.f ? v : 0.f;
}

extern "C" void kernel_launch(void* const* d_in, const int* in_sizes, int n_in,
                              void* d_out, int out_size, void* d_ws, size_t ws_size,
                              hipStream_t stream) {
    const float* f1     = (const float*)d_in[0];
    const int*   ei1    = (const int*)  d_in[1];
    const float* f2     = (const float*)d_in[2];
    const int*   ei2    = (const int*)  d_in[3];
    const float* W1     = (const float*)d_in[4];
    const float* b1     = (const float*)d_in[5];
    const float* W2     = (const float*)d_in[6];
    const float* b2     = (const float*)d_in[7];
    const float* W3     = (const float*)d_in[8];
    const float* b3     = (const float*)d_in[9];
    const float* W_att  = (const float*)d_in[10];
    const float* W_tn   = (const float*)d_in[11];
    const float* W_blk  = (const float*)d_in[12];
    const float* b_tn   = (const float*)d_in[13];

    int N = in_sizes[0] / 64;
    int E = in_sizes[1] / 2;
    int M = 2 * N;
    int E2 = 2 * E;
    int nsb = 11;
    while ((NSLICE << nsb) < M) nsb++;

    char* ws = (char*)d_ws;
    size_t off = 0;
    auto alloc = [&](size_t bytes) -> void* {
        void* p = ws + off;
        off += (bytes + 511) & ~(size_t)511;
        return p;
    };
    _Float16*  xsA     = (_Float16*) alloc((size_t)M * 64 * sizeof(_Float16)); // xs0; h3s reuse
    _Float16*  xsB     = (_Float16*) alloc((size_t)M * 64 * sizeof(_Float16)); // xs1
    _Float16*  tH      = (_Float16*) alloc((size_t)M * 64 * sizeof(_Float16)); // t1 / t2
    // a3 (f32, M*32) shares region with bkt (uint32, E2): bkt dies at fillC.
    size_t a3_bytes  = (size_t)M * 32 * sizeof(float);
    size_t bkt_bytes = (size_t)E2 * sizeof(unsigned);
    char*  region    = (char*)alloc(a3_bytes > bkt_bytes ? a3_bytes : bkt_bytes);
    float*    a3  = (float*)region;
    unsigned* bkt = (unsigned*)region;
    int*       col     = (int*)      alloc((size_t)E2 * sizeof(int));
    int*       row_ptr = (int*)      alloc((size_t)(M + 1) * sizeof(int));
    float*     dinv    = (float*)    alloc((size_t)M * sizeof(float));
    int*       gcnt    = (int*)      alloc((size_t)NSLICE * NBLK * sizeof(int));
    int*       sliceSt = (int*)      alloc((NSLICE + 1) * sizeof(int));
    _Float16*  pk      = (_Float16*) alloc(10240 * sizeof(_Float16));
    float*     smalls  = (float*)    alloc(256 * sizeof(float));
    float* msum   = smalls;
    float* pooled = smalls + 64;
    _Float16* pk1 = pk, *pk2 = pk + 4096, *pk3 = pk + 8192;

    hipMemsetAsync(smalls, 0, 256 * sizeof(float), stream);

    int chunk = (E2 + NBLK - 1) / NBLK;
    int lds_fused = ((1 << nsb) + 1024) * sizeof(int);

    // CSR build (packed-bkt — R23)
    bcount_kernel<<<NBLK, 256, 0, stream>>>(ei1, ei2, E, N, gcnt, chunk, nsb);
    bscan_kernel<<<1, 1024, 0, stream>>>(gcnt, sliceSt, row_ptr, M, E2);
    bwrite_kernel<<<NBLK, 256, 0, stream>>>(ei1, ei2, E, N, gcnt, bkt, chunk, nsb);
    fillC_fused_kernel<<<NSLICE, 1024, lds_fused, stream>>>(bkt, sliceSt, row_ptr, dinv, col, M, nsb);

    // Weight packing + pre-scaled f16 input table
    packW_kernel<<<40, 256, 0, stream>>>(W1, W2, W3, pk);
    int cvb = (M * 64 / 4 + 255) / 256;
    scale0_kernel<<<cvb, 256, 0, stream>>>(f1, f2, dinv, xsA, N * 64);

    // GCN stack; agg64 graph x feature-half split (R24): 4 * ceil(N*16/256).
    int nb64 = 4 * ((N * 16 + 255) / 256);
    int gw   = ((M / 16) + 3) / 4;
    agg64_kernel<<<nb64, 256, 0, stream>>>(xsA, tH, row_ptr, col, dinv, N);               // t1
    mfma_gemm64_kernel<<<gw, 256, 0, stream>>>(tH, xsB, pk1, b1, dinv, M);                // xs1
    agg64_kernel<<<nb64, 256, 0, stream>>>(xsB, tH, row_ptr, col, dinv, N);               // t2
    mfma_gemm64_32_kernel<<<gw, 256, 0, stream>>>(tH, xsA, pk2, pk3, b2, dinv, M);        // h3s

    const int HG = 512;   // SETTLED: R14 (thrash) + R20 (L2-fit) both regress at 1024
    agg32_colsum_kernel<<<2 * HG, 256, 0, stream>>>(xsA, a3, row_ptr, col, dinv, b3, msum, N, HG);

    pool2_kernel<<<2 * 256, 256, 0, stream>>>(a3, msum, W_att, pooled, N, 256);
    ntn_kernel<<<1, 64, 0, stream>>>(pooled, pooled + 32, W_tn, W_blk, b_tn, (float*)d_out);
}

// Round 11
// 335.772 us; speedup vs baseline: 1.0640x; 1.0640x over previous
//
#include <hip/hip_runtime.h>
#include <math.h>

// ---------------------------------------------------------------------------
// SimGNN forward on MI355X — R23 best (336.3 us) + agg64 f16x4 vectorization.
// R24 post-mortem: graph x feature-half split REGRESSED +21 us (agg32 rows
// unchanged — all on agg64). Halving request width DOUBLED request count;
// gathers are L2 request-rate bound (consolidates R20). RULE: reduce request
// count, never increase it. Split reverted.
// R25: inverse lever — agg64 gathers f16x2(4B/lane,32 lanes/row) ->
// f16x4(8B/lane,16 lanes/row): same 128B row per neighbor, VMEM instruction
// count halves, waves halve, col/row_ptr broadcast reads halve. Numerically
// identical (per-feature accumulation order unchanged).
// R23 WIN: packed-bkt uint32 CSR (345.4->336.3). R22 WIN: agg64 parity
// (−3.1). R20: HG=1024 regressed at const FETCH — agg32 L2 queue-bound;
// HG=512 SETTLED. R17 WIN: agg32 parity split (FETCH 54.8->19.2 MB).
// R16 WIN: countB+scans fused into fillC. R15: global atomics dead.
// Pipeline: bcount/bscan/bwrite -> fillC_fused(row_ptr,dinv,col)
//   -> scale0/packW -> agg64 -> mfma1 -> agg64 -> mfma2 -> agg32_colsum
//   -> pool(ctx recomputed per block) -> ntn
// ---------------------------------------------------------------------------

#define NSLICE 64
#define NBLK   256

typedef _Float16 f16x8 __attribute__((ext_vector_type(8)));
typedef _Float16 f16x4 __attribute__((ext_vector_type(4)));
typedef _Float16 f16x2 __attribute__((ext_vector_type(2)));
typedef float    f32x4 __attribute__((ext_vector_type(4)));

// ---- bucket phase A: per-block slice counts (R12 exact) ----
__global__ void bcount_kernel(const int* __restrict__ ei1, const int* __restrict__ ei2,
                              int E, int N, int* __restrict__ gcnt, int chunk, int nsb) {
    __shared__ int cnt[NSLICE];
    int t = threadIdx.x;
    if (t < NSLICE) cnt[t] = 0;
    __syncthreads();
    int E2 = 2 * E;
    int lo = blockIdx.x * chunk;
    int hi = lo + chunk; if (hi > E2) hi = E2;
    for (int i = lo + t; i < hi; i += blockDim.x) {
        int dst = (i < E) ? ei1[E + i] : (ei2[E + (i - E)] + N);
        atomicAdd(&cnt[dst >> nsb], 1);
    }
    __syncthreads();
    if (t < NSLICE) gcnt[t * NBLK + blockIdx.x] = cnt[t];
}

// ---- bucket phase B: exclusive scan of gcnt[64*NBLK]; also row_ptr[M]=E2 ----
__global__ void bscan_kernel(int* __restrict__ gcnt, int* __restrict__ sliceStart,
                             int* __restrict__ row_ptr, int M, int E2) {
    __shared__ int sh[1024];
    int t = threadIdx.x;
    const int PER = (NSLICE * NBLK) / 1024;
    int base = t * PER;
    int vals[PER];
    int s = 0;
    #pragma unroll
    for (int k = 0; k < PER; ++k) { vals[k] = gcnt[base + k]; s += vals[k]; }
    sh[t] = s;
    __syncthreads();
    for (int off = 1; off < 1024; off <<= 1) {
        int v = (t >= off) ? sh[t - off] : 0;
        __syncthreads();
        sh[t] += v;
        __syncthreads();
    }
    int run = (t == 0) ? 0 : sh[t - 1];
    #pragma unroll
    for (int k = 0; k < PER; ++k) {
        gcnt[base + k] = run;
        run += vals[k];
    }
    __syncthreads();
    if (t < NSLICE) sliceStart[t] = gcnt[t * NBLK];
    if (t == 0) { sliceStart[NSLICE] = E2; row_ptr[M] = E2; }
}

// ---- bucket phase C: place edges (R23: packed uint32) ----
// w = (src << nsb) | (dst & (2^nsb - 1)); src < 2^(32-nsb) required
// (M = 100K < 2^17 <= 2^21 at nsb=11 — holds with huge margin).
__global__ void bwrite_kernel(const int* __restrict__ ei1, const int* __restrict__ ei2,
                              int E, int N, const int* __restrict__ gcnt,
                              unsigned* __restrict__ bkt, int chunk, int nsb) {
    __shared__ int cur[NSLICE];
    int t = threadIdx.x;
    if (t < NSLICE) cur[t] = gcnt[t * NBLK + blockIdx.x];
    __syncthreads();
    int E2 = 2 * E;
    unsigned mask = (1u << nsb) - 1u;
    int lo = blockIdx.x * chunk;
    int hi = lo + chunk; if (hi > E2) hi = E2;
    for (int i = lo + t; i < hi; i += blockDim.x) {
        int src, dst;
        if (i < E) { src = ei1[i];         dst = ei1[E + i]; }
        else       { src = ei2[i - E] + N; dst = ei2[E + (i - E)] + N; }
        int p = atomicAdd(&cur[dst >> nsb], 1);
        bkt[p] = ((unsigned)src << nsb) | ((unsigned)dst & mask);
    }
}

// ---- fillC_fused: one block per slice. Phase 1: LDS histogram of the
// slice's dsts (low nsb bits of packed word). Phase 2: LDS block-scan ->
// row_ptr/dinv (global base = sliceStart[slice]). Phase 3: place col via
// LDS cursors (hold global positions). No global atomics.
__global__ void fillC_fused_kernel(const unsigned* __restrict__ bkt,
                                   const int* __restrict__ sliceStart,
                                   int* __restrict__ row_ptr, float* __restrict__ dinv,
                                   int* __restrict__ col, int M, int nsb) {
    extern __shared__ int sm[];           // [nbins] hist/cursor + [1024] scan
    int nbins = 1 << nsb;
    unsigned mask = (unsigned)nbins - 1u;
    int* hist = sm;
    int* ssum = sm + nbins;
    int slice = blockIdx.x;
    int lo = slice << nsb;
    int t = threadIdx.x;                  // blockDim.x == 1024
    for (int j = t; j < nbins; j += 1024) hist[j] = 0;
    __syncthreads();
    int s = sliceStart[slice], e = sliceStart[slice + 1];
    // Phase 1: histogram over low bits
    for (int i = s + t; i < e; i += 1024)
        atomicAdd(&hist[bkt[i] & mask], 1);
    __syncthreads();
    // Phase 2: exclusive scan over nbins (PER bins per thread)
    const int PER = nbins >> 10;          // nbins/1024 (2 for nsb=11)
    int base = t * PER;
    int vals[4];                          // supports nsb up to 12
    int acc = 0;
    for (int k = 0; k < PER; ++k) { vals[k] = hist[base + k]; acc += vals[k]; }
    ssum[t] = acc;
    __syncthreads();
    for (int off = 1; off < 1024; off <<= 1) {
        int v = (t >= off) ? ssum[t - off] : 0;
        __syncthreads();
        ssum[t] += v;
        __syncthreads();
    }
    int run = s + ((t == 0) ? 0 : ssum[t - 1]);
    for (int k = 0; k < PER; ++k) {
        int idx = lo + base + k;
        if (idx < M) {
            row_ptr[idx] = run;
            dinv[idx] = rsqrtf((float)(vals[k] + 1));
        }
        hist[base + k] = run;             // becomes the global write cursor
        run += vals[k];
    }
    __syncthreads();
    // Phase 3: place edges (src = high bits)
    for (int i = s + t; i < e; i += 1024) {
        unsigned w = bkt[i];
        int p = atomicAdd(&hist[w & mask], 1);
        col[p] = (int)(w >> nsb);
    }
}

// xs0[i] = f16(x0[i] * dinv[i/64]); 4 elements per thread.
__global__ void scale0_kernel(const float* __restrict__ f1, const float* __restrict__ f2,
                              const float* __restrict__ dinv, _Float16* __restrict__ xs,
                              int n /* = N*64 */) {
    int i4 = (blockIdx.x * blockDim.x + threadIdx.x) * 4;
    if (i4 >= 2 * n) return;
    const float* src = (i4 < n) ? (f1 + i4) : (f2 + (i4 - n));
    float dv = dinv[i4 >> 6];
    float4 v = *(const float4*)src;
    f16x4 o = { (_Float16)(v.x * dv), (_Float16)(v.y * dv),
                (_Float16)(v.z * dv), (_Float16)(v.w * dv) };
    *(f16x4*)(xs + i4) = o;
}

// Pack W1,W2 (64x64) and W3 (64x32) into MFMA B-fragment order, f16.
__global__ void packW_kernel(const float* __restrict__ W1, const float* __restrict__ W2,
                             const float* __restrict__ W3, _Float16* __restrict__ pk) {
    int t = blockIdx.x * blockDim.x + threadIdx.x;
    if (t < 8192) {
        const float* W = (t < 4096) ? W1 : W2;
        int idx = t & 4095;
        int j = idx & 7, slot = idx >> 3;
        int lane = slot & 63, s = (slot >> 6) & 1, ct = slot >> 7;
        int k = s * 32 + ((lane >> 4) << 3) + j;
        int n = ct * 16 + (lane & 15);
        pk[t] = (_Float16)W[k * 64 + n];
    } else if (t < 10240) {
        int idx = t - 8192;
        int j = idx & 7, slot = idx >> 3;
        int lane = slot & 63, s = (slot >> 6) & 1, ct = slot >> 7;
        int k = s * 32 + ((lane >> 4) << 3) + j;
        int n = ct * 16 + (lane & 15);
        pk[t] = (_Float16)W3[k * 32 + n];
    }
}

// R25: quarter-wave per node, f16x4 (8B) per lane — same 128B row per
// neighbor as R22's half-wave f16x2, but half the VMEM instructions and
// half the waves (request-COUNT reduction; R24 taught width reduction is
// the wrong direction). g = blockIdx&1 parity split kept (R22, −3 us).
// Numerically identical: per-feature accumulation order unchanged.
__global__ void agg64_kernel(const _Float16* __restrict__ xs, _Float16* __restrict__ out,
                             const int* __restrict__ row_ptr, const int* __restrict__ col,
                             const float* __restrict__ dinv, int N) {
    int g = blockIdx.x & 1;
    int nv = ((blockIdx.x >> 1) * blockDim.x + threadIdx.x) >> 4;
    int l = threadIdx.x & 15;
    if (nv >= N) return;
    int v = g * N + nv;
    const f16x4* row = (const f16x4*)(xs + (size_t)v * 64);
    f16x4 sv = row[l];
    float a0 = (float)sv[0], a1 = (float)sv[1], a2 = (float)sv[2], a3 = (float)sv[3];
    int s = row_ptr[v], e = row_ptr[v + 1];
    int i = s;
    for (; i + 8 <= e; i += 8) {
        int u0 = col[i],     u1 = col[i + 1], u2 = col[i + 2], u3 = col[i + 3];
        int u4 = col[i + 4], u5 = col[i + 5], u6 = col[i + 6], u7 = col[i + 7];
        f16x4 p0 = ((const f16x4*)(xs + (size_t)u0 * 64))[l];
        f16x4 p1 = ((const f16x4*)(xs + (size_t)u1 * 64))[l];
        f16x4 p2 = ((const f16x4*)(xs + (size_t)u2 * 64))[l];
        f16x4 p3 = ((const f16x4*)(xs + (size_t)u3 * 64))[l];
        f16x4 p4 = ((const f16x4*)(xs + (size_t)u4 * 64))[l];
        f16x4 p5 = ((const f16x4*)(xs + (size_t)u5 * 64))[l];
        f16x4 p6 = ((const f16x4*)(xs + (size_t)u6 * 64))[l];
        f16x4 p7 = ((const f16x4*)(xs + (size_t)u7 * 64))[l];
        a0 += (((float)p0[0] + (float)p1[0]) + ((float)p2[0] + (float)p3[0]))
            + (((float)p4[0] + (float)p5[0]) + ((float)p6[0] + (float)p7[0]));
        a1 += (((float)p0[1] + (float)p1[1]) + ((float)p2[1] + (float)p3[1]))
            + (((float)p4[1] + (float)p5[1]) + ((float)p6[1] + (float)p7[1]));
        a2 += (((float)p0[2] + (float)p1[2]) + ((float)p2[2] + (float)p3[2]))
            + (((float)p4[2] + (float)p5[2]) + ((float)p6[2] + (float)p7[2]));
        a3 += (((float)p0[3] + (float)p1[3]) + ((float)p2[3] + (float)p3[3]))
            + (((float)p4[3] + (float)p5[3]) + ((float)p6[3] + (float)p7[3]));
    }
    for (; i + 4 <= e; i += 4) {
        int u0 = col[i], u1 = col[i + 1], u2 = col[i + 2], u3 = col[i + 3];
        f16x4 p0 = ((const f16x4*)(xs + (size_t)u0 * 64))[l];
        f16x4 p1 = ((const f16x4*)(xs + (size_t)u1 * 64))[l];
        f16x4 p2 = ((const f16x4*)(xs + (size_t)u2 * 64))[l];
        f16x4 p3 = ((const f16x4*)(xs + (size_t)u3 * 64))[l];
        a0 += ((float)p0[0] + (float)p1[0]) + ((float)p2[0] + (float)p3[0]);
        a1 += ((float)p0[1] + (float)p1[1]) + ((float)p2[1] + (float)p3[1]);
        a2 += ((float)p0[2] + (float)p1[2]) + ((float)p2[2] + (float)p3[2]);
        a3 += ((float)p0[3] + (float)p1[3]) + ((float)p2[3] + (float)p3[3]);
    }
    for (; i < e; ++i) {
        f16x4 p = ((const f16x4*)(xs + (size_t)col[i] * 64))[l];
        a0 += (float)p[0]; a1 += (float)p[1]; a2 += (float)p[2]; a3 += (float)p[3];
    }
    float dv = dinv[v];
    f16x4 o = { (_Float16)(a0 * dv), (_Float16)(a1 * dv),
                (_Float16)(a2 * dv), (_Float16)(a3 * dv) };
    ((f16x4*)(out + (size_t)v * 64))[l] = o;
}

// MFMA GEMM: xs1 = f16(relu(t@W1+b1)*dinv). Wave = 16 rows x 64 cols, K=64.
__global__ void mfma_gemm64_kernel(const _Float16* __restrict__ tA, _Float16* __restrict__ out,
                                   const _Float16* __restrict__ pk, const float* __restrict__ b1,
                                   const float* __restrict__ dinv, int M) {
    int wave = (blockIdx.x * blockDim.x + threadIdx.x) >> 6;
    int lane = threadIdx.x & 63;
    int base = wave * 16;
    if (base >= M) return;
    int l15 = lane & 15, q = lane >> 4;
    const f16x8* arow = (const f16x8*)(tA + (size_t)(base + l15) * 64);
    f16x8 a0 = arow[q];
    f16x8 a1 = arow[q + 4];
    const f16x8* bp = (const f16x8*)pk;
    f32x4 acc[4];
    #pragma unroll
    for (int ct = 0; ct < 4; ++ct) {
        f32x4 c = {0.f, 0.f, 0.f, 0.f};
        c = __builtin_amdgcn_mfma_f32_16x16x32_f16(a0, bp[(ct * 2 + 0) * 64 + lane], c, 0, 0, 0);
        c = __builtin_amdgcn_mfma_f32_16x16x32_f16(a1, bp[(ct * 2 + 1) * 64 + lane], c, 0, 0, 0);
        acc[ct] = c;
    }
    float dv[4];
    #pragma unroll
    for (int r = 0; r < 4; ++r) dv[r] = dinv[base + q * 4 + r];
    #pragma unroll
    for (int ct = 0; ct < 4; ++ct) {
        float bj = b1[ct * 16 + l15];
        #pragma unroll
        for (int r = 0; r < 4; ++r)
            out[(size_t)(base + q * 4 + r) * 64 + ct * 16 + l15] =
                (_Float16)(fmaxf(acc[ct][r] + bj, 0.f) * dv[r]);
    }
}

// MFMA double GEMM: h3s = f16((relu(t@W2+b2)@W3)*dinv). LDS transpose between.
__global__ void mfma_gemm64_32_kernel(const _Float16* __restrict__ tA, _Float16* __restrict__ out,
                                      const _Float16* __restrict__ pk2, const _Float16* __restrict__ pk3,
                                      const float* __restrict__ b2, const float* __restrict__ dinv,
                                      int M) {
    __shared__ _Float16 xl[4][16][72];
    int wv = threadIdx.x >> 6;
    int wave = (blockIdx.x * blockDim.x + threadIdx.x) >> 6;
    int lane = threadIdx.x & 63;
    int base = wave * 16;
    if (base >= M) return;
    int l15 = lane & 15, q = lane >> 4;
    const f16x8* arow = (const f16x8*)(tA + (size_t)(base + l15) * 64);
    f16x8 a0 = arow[q];
    f16x8 a1 = arow[q + 4];
    const f16x8* bp2 = (const f16x8*)pk2;
    #pragma unroll
    for (int ct = 0; ct < 4; ++ct) {
        f32x4 c = {0.f, 0.f, 0.f, 0.f};
        c = __builtin_amdgcn_mfma_f32_16x16x32_f16(a0, bp2[(ct * 2 + 0) * 64 + lane], c, 0, 0, 0);
        c = __builtin_amdgcn_mfma_f32_16x16x32_f16(a1, bp2[(ct * 2 + 1) * 64 + lane], c, 0, 0, 0);
        float bj = b2[ct * 16 + l15];
        #pragma unroll
        for (int r = 0; r < 4; ++r)
            xl[wv][q * 4 + r][ct * 16 + l15] = (_Float16)fmaxf(c[r] + bj, 0.f);
    }
    const f16x8* xr = (const f16x8*)(&xl[wv][l15][0]);
    f16x8 e0 = xr[q];
    f16x8 e1 = xr[q + 4];
    const f16x8* bp3 = (const f16x8*)pk3;
    float dv[4];
    #pragma unroll
    for (int r = 0; r < 4; ++r) dv[r] = dinv[base + q * 4 + r];
    #pragma unroll
    for (int ct = 0; ct < 2; ++ct) {
        f32x4 c = {0.f, 0.f, 0.f, 0.f};
        c = __builtin_amdgcn_mfma_f32_16x16x32_f16(e0, bp3[(ct * 2 + 0) * 64 + lane], c, 0, 0, 0);
        c = __builtin_amdgcn_mfma_f32_16x16x32_f16(e1, bp3[(ct * 2 + 1) * 64 + lane], c, 0, 0, 0);
        #pragma unroll
        for (int r = 0; r < 4; ++r)
            out[(size_t)(base + q * 4 + r) * 32 + ct * 16 + l15] = (_Float16)(c[r] * dv[r]);
    }
}

// agg32: quarter-wave per node; a3 f32 out; fused colsums.
// R17: g = blockIdx&1 — parity split: per-XCD gather set 3.2 MB < 4 MB L2
// (FETCH 54.8->19.2 MB). HG=512 SETTLED (R14 + R20: x2 regresses in both
// thrash and L2-fit regimes — L2 queue-bound, not wave-starved).
__global__ void agg32_colsum_kernel(const _Float16* __restrict__ hs, float* __restrict__ out,
                                    const int* __restrict__ row_ptr, const int* __restrict__ col,
                                    const float* __restrict__ dinv, const float* __restrict__ b,
                                    float* __restrict__ msum, int N, int halfgrid) {
    int g = blockIdx.x & 1;
    int bid = blockIdx.x >> 1;
    int t = threadIdx.x;
    int l = t & 15;
    int qw = (bid * blockDim.x + t) >> 4;
    int nqw = (halfgrid * blockDim.x) >> 4;
    float blx = b[2 * l], bly = b[2 * l + 1];
    float csx = 0.f, csy = 0.f;
    int base = g * N;
    for (int vv = qw; vv < N; vv += nqw) {
        int v = base + vv;
        f16x2 sv = ((const f16x2*)(hs + (size_t)v * 32))[l];
        float ax = (float)sv.x, ay = (float)sv.y;
        int s = row_ptr[v], e = row_ptr[v + 1];
        int i = s;
        for (; i + 8 <= e; i += 8) {
            int u0 = col[i],     u1 = col[i + 1], u2 = col[i + 2], u3 = col[i + 3];
            int u4 = col[i + 4], u5 = col[i + 5], u6 = col[i + 6], u7 = col[i + 7];
            f16x2 p0 = ((const f16x2*)(hs + (size_t)u0 * 32))[l];
            f16x2 p1 = ((const f16x2*)(hs + (size_t)u1 * 32))[l];
            f16x2 p2 = ((const f16x2*)(hs + (size_t)u2 * 32))[l];
            f16x2 p3 = ((const f16x2*)(hs + (size_t)u3 * 32))[l];
            f16x2 p4 = ((const f16x2*)(hs + (size_t)u4 * 32))[l];
            f16x2 p5 = ((const f16x2*)(hs + (size_t)u5 * 32))[l];
            f16x2 p6 = ((const f16x2*)(hs + (size_t)u6 * 32))[l];
            f16x2 p7 = ((const f16x2*)(hs + (size_t)u7 * 32))[l];
            ax += (((float)p0.x + (float)p1.x) + ((float)p2.x + (float)p3.x))
                + (((float)p4.x + (float)p5.x) + ((float)p6.x + (float)p7.x));
            ay += (((float)p0.y + (float)p1.y) + ((float)p2.y + (float)p3.y))
                + (((float)p4.y + (float)p5.y) + ((float)p6.y + (float)p7.y));
        }
        for (; i + 4 <= e; i += 4) {
            int u0 = col[i], u1 = col[i + 1], u2 = col[i + 2], u3 = col[i + 3];
            f16x2 p0 = ((const f16x2*)(hs + (size_t)u0 * 32))[l];
            f16x2 p1 = ((const f16x2*)(hs + (size_t)u1 * 32))[l];
            f16x2 p2 = ((const f16x2*)(hs + (size_t)u2 * 32))[l];
            f16x2 p3 = ((const f16x2*)(hs + (size_t)u3 * 32))[l];
            ax += ((float)p0.x + (float)p1.x) + ((float)p2.x + (float)p3.x);
            ay += ((float)p0.y + (float)p1.y) + ((float)p2.y + (float)p3.y);
        }
        for (; i < e; ++i) {
            f16x2 p = ((const f16x2*)(hs + (size_t)col[i] * 32))[l];
            ax += (float)p.x; ay += (float)p.y;
        }
        float dv = dinv[v];
        float ox = ax * dv + blx, oy = ay * dv + bly;
        *(float2*)(out + (size_t)v * 32 + 2 * l) = make_float2(ox, oy);
        csx += ox; csy += oy;
    }
    __shared__ float spx[256], spy[256];
    spx[t] = csx; spy[t] = csy;
    __syncthreads();
    if (t < 16) {
        float sx = 0.f, sy = 0.f;
        for (int w = 0; w < 16; ++w) { sx += spx[w * 16 + t]; sy += spy[w * 16 + t]; }
        atomicAdd(&msum[g * 32 + 2 * t], sx);
        atomicAdd(&msum[g * 32 + 2 * t + 1], sy);
    }
}

// pool with ctx recomputed per block (ctx2 kernel fused away):
// ctx[j] = tanh(sum_i (msum[i]/N) * W_att[i][j]) — 1K FLOPs per block.
__global__ void pool2_kernel(const float* __restrict__ a3, const float* __restrict__ msum,
                             const float* __restrict__ W_att, float* __restrict__ pooled,
                             int N, int halfgrid) {
    int g = (blockIdx.x >= halfgrid) ? 1 : 0;
    int bid = blockIdx.x - g * halfgrid;
    int t = threadIdx.x;
    int j = t & 31;
    float invN = 1.f / (float)N;
    float acc = 0.f;
    for (int i = 0; i < 32; ++i) acc += (msum[g * 32 + i] * invN) * W_att[i * 32 + j];
    float cj = tanhf(acc);
    int hw = (bid * blockDim.x + t) >> 5;
    int nhw = (halfgrid * blockDim.x) >> 5;
    const float* base = a3 + (size_t)g * N * 32;
    float local = 0.f;
    for (int n = hw; n < N; n += nhw) {
        float v = base[(size_t)n * 32 + j];
        float d = v * cj;
        #pragma unroll
        for (int off = 16; off; off >>= 1) d += __shfl_xor(d, off);
        float s = 1.f / (1.f + __expf(-d));
        local += s * v;
    }
    __shared__ float sp[256];
    sp[t] = local;
    __syncthreads();
    if (t < 32) {
        float s = 0.f;
        for (int w = 0; w < 8; ++w) s += sp[w * 32 + t];
        atomicAdd(&pooled[g * 32 + t], s);
    }
}

__global__ void ntn_kernel(const float* __restrict__ p1, const float* __restrict__ p2,
                           const float* __restrict__ W_tn, const float* __restrict__ W_block,
                           const float* __restrict__ b_tn, float* __restrict__ out) {
    int k = threadIdx.x;
    if (k >= 16) return;
    float sc = 0.f;
    for (int i = 0; i < 32; ++i) {
        float e1 = p1[i];
        for (int j = 0; j < 32; ++j) sc += e1 * W_tn[i * 512 + j * 16 + k] * p2[j];
    }
    float bl = 0.f;
    for (int j = 0; j < 32; ++j)
        bl += W_block[k * 64 + j] * p1[j] + W_block[k * 64 + 32 + j] * p2[j];
    float v = sc + bl + b_tn[k];
    out[k] = v > 0.f ? v : 0.f;
}

extern "C" void kernel_launch(void* const* d_in, const int* in_sizes, int n_in,
                              void* d_out, int out_size, void* d_ws, size_t ws_size,
                              hipStream_t stream) {
    const float* f1     = (const float*)d_in[0];
    const int*   ei1    = (const int*)  d_in[1];
    const float* f2     = (const float*)d_in[2];
    const int*   ei2    = (const int*)  d_in[3];
    const float* W1     = (const float*)d_in[4];
    const float* b1     = (const float*)d_in[5];
    const float* W2     = (const float*)d_in[6];
    const float* b2     = (const float*)d_in[7];
    const float* W3     = (const float*)d_in[8];
    const float* b3     = (const float*)d_in[9];
    const float* W_att  = (const float*)d_in[10];
    const float* W_tn   = (const float*)d_in[11];
    const float* W_blk  = (const float*)d_in[12];
    const float* b_tn   = (const float*)d_in[13];

    int N = in_sizes[0] / 64;
    int E = in_sizes[1] / 2;
    int M = 2 * N;
    int E2 = 2 * E;
    int nsb = 11;
    while ((NSLICE << nsb) < M) nsb++;

    char* ws = (char*)d_ws;
    size_t off = 0;
    auto alloc = [&](size_t bytes) -> void* {
        void* p = ws + off;
        off += (bytes + 511) & ~(size_t)511;
        return p;
    };
    _Float16*  xsA     = (_Float16*) alloc((size_t)M * 64 * sizeof(_Float16)); // xs0; h3s reuse
    _Float16*  xsB     = (_Float16*) alloc((size_t)M * 64 * sizeof(_Float16)); // xs1
    _Float16*  tH      = (_Float16*) alloc((size_t)M * 64 * sizeof(_Float16)); // t1 / t2
    // a3 (f32, M*32) shares region with bkt (uint32, E2): bkt dies at fillC.
    size_t a3_bytes  = (size_t)M * 32 * sizeof(float);
    size_t bkt_bytes = (size_t)E2 * sizeof(unsigned);
    char*  region    = (char*)alloc(a3_bytes > bkt_bytes ? a3_bytes : bkt_bytes);
    float*    a3  = (float*)region;
    unsigned* bkt = (unsigned*)region;
    int*       col     = (int*)      alloc((size_t)E2 * sizeof(int));
    int*       row_ptr = (int*)      alloc((size_t)(M + 1) * sizeof(int));
    float*     dinv    = (float*)    alloc((size_t)M * sizeof(float));
    int*       gcnt    = (int*)      alloc((size_t)NSLICE * NBLK * sizeof(int));
    int*       sliceSt = (int*)      alloc((NSLICE + 1) * sizeof(int));
    _Float16*  pk      = (_Float16*) alloc(10240 * sizeof(_Float16));
    float*     smalls  = (float*)    alloc(256 * sizeof(float));
    float* msum   = smalls;
    float* pooled = smalls + 64;
    _Float16* pk1 = pk, *pk2 = pk + 4096, *pk3 = pk + 8192;

    hipMemsetAsync(smalls, 0, 256 * sizeof(float), stream);

    int chunk = (E2 + NBLK - 1) / NBLK;
    int lds_fused = ((1 << nsb) + 1024) * sizeof(int);

    // CSR build (packed-bkt — R23)
    bcount_kernel<<<NBLK, 256, 0, stream>>>(ei1, ei2, E, N, gcnt, chunk, nsb);
    bscan_kernel<<<1, 1024, 0, stream>>>(gcnt, sliceSt, row_ptr, M, E2);
    bwrite_kernel<<<NBLK, 256, 0, stream>>>(ei1, ei2, E, N, gcnt, bkt, chunk, nsb);
    fillC_fused_kernel<<<NSLICE, 1024, lds_fused, stream>>>(bkt, sliceSt, row_ptr, dinv, col, M, nsb);

    // Weight packing + pre-scaled f16 input table
    packW_kernel<<<40, 256, 0, stream>>>(W1, W2, W3, pk);
    int cvb = (M * 64 / 4 + 255) / 256;
    scale0_kernel<<<cvb, 256, 0, stream>>>(f1, f2, dinv, xsA, N * 64);

    // GCN stack; agg64 parity + f16x4 quarter-wave (R25): 2 * ceil(N*16/256).
    int nb64 = 2 * ((N * 16 + 255) / 256);
    int gw   = ((M / 16) + 3) / 4;
    agg64_kernel<<<nb64, 256, 0, stream>>>(xsA, tH, row_ptr, col, dinv, N);               // t1
    mfma_gemm64_kernel<<<gw, 256, 0, stream>>>(tH, xsB, pk1, b1, dinv, M);                // xs1
    agg64_kernel<<<nb64, 256, 0, stream>>>(xsB, tH, row_ptr, col, dinv, N);               // t2
    mfma_gemm64_32_kernel<<<gw, 256, 0, stream>>>(tH, xsA, pk2, pk3, b2, dinv, M);        // h3s

    const int HG = 512;   // SETTLED: R14 (thrash) + R20 (L2-fit) both regress at 1024
    agg32_colsum_kernel<<<2 * HG, 256, 0, stream>>>(xsA, a3, row_ptr, col, dinv, b3, msum, N, HG);

    pool2_kernel<<<2 * 256, 256, 0, stream>>>(a3, msum, W_att, pooled, N, 256);
    ntn_kernel<<<1, 64, 0, stream>>>(pooled, pooled + 32, W_tn, W_blk, b_tn, (float*)d_out);
}

// Round 13
// 318.259 us; speedup vs baseline: 1.1225x; 1.0550x over previous
//
#include <hip/hip_runtime.h>
#include <math.h>

// ---------------------------------------------------------------------------
// SimGNN forward on MI355X — R25 best (335.8 us) + agg+GEMM fusion (R27).
// R26 post-mortem: "container failed twice" (NEW failure mode, not broker
// timeout). Most likely culprit: the last-block-flag NTN tail (cross-XCD
// flag + coherent reads under graph replay). R27 drops that construct
// (pool2/ntn restored R25-exact) and keeps the two routine fusions:
// (1) agg64+mfma1 -> agg_gemm1: block's 16 quarter-waves produce exactly
//     the 16 rows one MFMA tile needs; gather -> LDS[16][72] -> 4 waves.
// (2) agg64+mfma2 -> agg_gemm2 (W2 relu -> LDS2 -> W3 tail).
// Kills both tH round-trips (51 MB) + 2 launches. Numerics bit-identical.
// R25: gathers L2 request-rate bound (R20/R24/R25 triangulation) — internal
// structure frozen; f16x4 quarter-wave gather kept verbatim.
// R23 WIN: packed-bkt uint32 CSR. R22 WIN: agg64 parity. R20: HG=512
// SETTLED. R17 WIN: agg32 parity (FETCH 54.8->19.2 MB). R16 WIN: fused
// fillC. R15: scattered global atomics dead.
// Pipeline: bcount/bscan/bwrite -> fillC_fused -> packW/scale0
//   -> agg_gemm1 -> agg_gemm2 -> agg32_colsum -> pool2 -> ntn
// ---------------------------------------------------------------------------

#define NSLICE 64
#define NBLK   256

typedef _Float16 f16x8 __attribute__((ext_vector_type(8)));
typedef _Float16 f16x4 __attribute__((ext_vector_type(4)));
typedef _Float16 f16x2 __attribute__((ext_vector_type(2)));
typedef float    f32x4 __attribute__((ext_vector_type(4)));

// ---- bucket phase A: per-block slice counts (R12 exact) ----
__global__ void bcount_kernel(const int* __restrict__ ei1, const int* __restrict__ ei2,
                              int E, int N, int* __restrict__ gcnt, int chunk, int nsb) {
    __shared__ int cnt[NSLICE];
    int t = threadIdx.x;
    if (t < NSLICE) cnt[t] = 0;
    __syncthreads();
    int E2 = 2 * E;
    int lo = blockIdx.x * chunk;
    int hi = lo + chunk; if (hi > E2) hi = E2;
    for (int i = lo + t; i < hi; i += blockDim.x) {
        int dst = (i < E) ? ei1[E + i] : (ei2[E + (i - E)] + N);
        atomicAdd(&cnt[dst >> nsb], 1);
    }
    __syncthreads();
    if (t < NSLICE) gcnt[t * NBLK + blockIdx.x] = cnt[t];
}

// ---- bucket phase B: exclusive scan of gcnt[64*NBLK]; also row_ptr[M]=E2 ----
__global__ void bscan_kernel(int* __restrict__ gcnt, int* __restrict__ sliceStart,
                             int* __restrict__ row_ptr, int M, int E2) {
    __shared__ int sh[1024];
    int t = threadIdx.x;
    const int PER = (NSLICE * NBLK) / 1024;
    int base = t * PER;
    int vals[PER];
    int s = 0;
    #pragma unroll
    for (int k = 0; k < PER; ++k) { vals[k] = gcnt[base + k]; s += vals[k]; }
    sh[t] = s;
    __syncthreads();
    for (int off = 1; off < 1024; off <<= 1) {
        int v = (t >= off) ? sh[t - off] : 0;
        __syncthreads();
        sh[t] += v;
        __syncthreads();
    }
    int run = (t == 0) ? 0 : sh[t - 1];
    #pragma unroll
    for (int k = 0; k < PER; ++k) {
        gcnt[base + k] = run;
        run += vals[k];
    }
    __syncthreads();
    if (t < NSLICE) sliceStart[t] = gcnt[t * NBLK];
    if (t == 0) { sliceStart[NSLICE] = E2; row_ptr[M] = E2; }
}

// ---- bucket phase C: place edges (R23: packed uint32) ----
__global__ void bwrite_kernel(const int* __restrict__ ei1, const int* __restrict__ ei2,
                              int E, int N, const int* __restrict__ gcnt,
                              unsigned* __restrict__ bkt, int chunk, int nsb) {
    __shared__ int cur[NSLICE];
    int t = threadIdx.x;
    if (t < NSLICE) cur[t] = gcnt[t * NBLK + blockIdx.x];
    __syncthreads();
    int E2 = 2 * E;
    unsigned mask = (1u << nsb) - 1u;
    int lo = blockIdx.x * chunk;
    int hi = lo + chunk; if (hi > E2) hi = E2;
    for (int i = lo + t; i < hi; i += blockDim.x) {
        int src, dst;
        if (i < E) { src = ei1[i];         dst = ei1[E + i]; }
        else       { src = ei2[i - E] + N; dst = ei2[E + (i - E)] + N; }
        int p = atomicAdd(&cur[dst >> nsb], 1);
        bkt[p] = ((unsigned)src << nsb) | ((unsigned)dst & mask);
    }
}

// ---- fillC_fused: histogram + intra-slice scan + col placement (R16/R23) ----
__global__ void fillC_fused_kernel(const unsigned* __restrict__ bkt,
                                   const int* __restrict__ sliceStart,
                                   int* __restrict__ row_ptr, float* __restrict__ dinv,
                                   int* __restrict__ col, int M, int nsb) {
    extern __shared__ int sm[];           // [nbins] hist/cursor + [1024] scan
    int nbins = 1 << nsb;
    unsigned mask = (unsigned)nbins - 1u;
    int* hist = sm;
    int* ssum = sm + nbins;
    int slice = blockIdx.x;
    int lo = slice << nsb;
    int t = threadIdx.x;                  // blockDim.x == 1024
    for (int j = t; j < nbins; j += 1024) hist[j] = 0;
    __syncthreads();
    int s = sliceStart[slice], e = sliceStart[slice + 1];
    for (int i = s + t; i < e; i += 1024)
        atomicAdd(&hist[bkt[i] & mask], 1);
    __syncthreads();
    const int PER = nbins >> 10;
    int base = t * PER;
    int vals[4];
    int acc = 0;
    for (int k = 0; k < PER; ++k) { vals[k] = hist[base + k]; acc += vals[k]; }
    ssum[t] = acc;
    __syncthreads();
    for (int off = 1; off < 1024; off <<= 1) {
        int v = (t >= off) ? ssum[t - off] : 0;
        __syncthreads();
        ssum[t] += v;
        __syncthreads();
    }
    int run = s + ((t == 0) ? 0 : ssum[t - 1]);
    for (int k = 0; k < PER; ++k) {
        int idx = lo + base + k;
        if (idx < M) {
            row_ptr[idx] = run;
            dinv[idx] = rsqrtf((float)(vals[k] + 1));
        }
        hist[base + k] = run;
        run += vals[k];
    }
    __syncthreads();
    for (int i = s + t; i < e; i += 1024) {
        unsigned w = bkt[i];
        int p = atomicAdd(&hist[w & mask], 1);
        col[p] = (int)(w >> nsb);
    }
}

// xs0[i] = f16(x0[i] * dinv[i/64]); 4 elements per thread.
__global__ void scale0_kernel(const float* __restrict__ f1, const float* __restrict__ f2,
                              const float* __restrict__ dinv, _Float16* __restrict__ xs,
                              int n /* = N*64 */) {
    int i4 = (blockIdx.x * blockDim.x + threadIdx.x) * 4;
    if (i4 >= 2 * n) return;
    const float* src = (i4 < n) ? (f1 + i4) : (f2 + (i4 - n));
    float dv = dinv[i4 >> 6];
    float4 v = *(const float4*)src;
    f16x4 o = { (_Float16)(v.x * dv), (_Float16)(v.y * dv),
                (_Float16)(v.z * dv), (_Float16)(v.w * dv) };
    *(f16x4*)(xs + i4) = o;
}

// Pack W1,W2 (64x64) and W3 (64x32) into MFMA B-fragment order, f16.
__global__ void packW_kernel(const float* __restrict__ W1, const float* __restrict__ W2,
                             const float* __restrict__ W3, _Float16* __restrict__ pk) {
    int t = blockIdx.x * blockDim.x + threadIdx.x;
    if (t < 8192) {
        const float* W = (t < 4096) ? W1 : W2;
        int idx = t & 4095;
        int j = idx & 7, slot = idx >> 3;
        int lane = slot & 63, s = (slot >> 6) & 1, ct = slot >> 7;
        int k = s * 32 + ((lane >> 4) << 3) + j;
        int n = ct * 16 + (lane & 15);
        pk[t] = (_Float16)W[k * 64 + n];
    } else if (t < 10240) {
        int idx = t - 8192;
        int j = idx & 7, slot = idx >> 3;
        int lane = slot & 63, s = (slot >> 6) & 1, ct = slot >> 7;
        int k = s * 32 + ((lane >> 4) << 3) + j;
        int n = ct * 16 + (lane & 15);
        pk[t] = (_Float16)W3[k * 32 + n];
    }
}

// Gather one node's 64-f16 row (f16x4 lane slice), R25-exact loop.
__device__ inline void gather_row4(const _Float16* __restrict__ xs,
                                   const int* __restrict__ row_ptr,
                                   const int* __restrict__ col,
                                   int v, int l, float a[4]) {
    const f16x4* row = (const f16x4*)(xs + (size_t)v * 64);
    f16x4 sv = row[l];
    a[0] = (float)sv[0]; a[1] = (float)sv[1]; a[2] = (float)sv[2]; a[3] = (float)sv[3];
    int s = row_ptr[v], e = row_ptr[v + 1];
    int i = s;
    for (; i + 8 <= e; i += 8) {
        int u0 = col[i],     u1 = col[i + 1], u2 = col[i + 2], u3 = col[i + 3];
        int u4 = col[i + 4], u5 = col[i + 5], u6 = col[i + 6], u7 = col[i + 7];
        f16x4 p0 = ((const f16x4*)(xs + (size_t)u0 * 64))[l];
        f16x4 p1 = ((const f16x4*)(xs + (size_t)u1 * 64))[l];
        f16x4 p2 = ((const f16x4*)(xs + (size_t)u2 * 64))[l];
        f16x4 p3 = ((const f16x4*)(xs + (size_t)u3 * 64))[l];
        f16x4 p4 = ((const f16x4*)(xs + (size_t)u4 * 64))[l];
        f16x4 p5 = ((const f16x4*)(xs + (size_t)u5 * 64))[l];
        f16x4 p6 = ((const f16x4*)(xs + (size_t)u6 * 64))[l];
        f16x4 p7 = ((const f16x4*)(xs + (size_t)u7 * 64))[l];
        a[0] += (((float)p0[0] + (float)p1[0]) + ((float)p2[0] + (float)p3[0]))
              + (((float)p4[0] + (float)p5[0]) + ((float)p6[0] + (float)p7[0]));
        a[1] += (((float)p0[1] + (float)p1[1]) + ((float)p2[1] + (float)p3[1]))
              + (((float)p4[1] + (float)p5[1]) + ((float)p6[1] + (float)p7[1]));
        a[2] += (((float)p0[2] + (float)p1[2]) + ((float)p2[2] + (float)p3[2]))
              + (((float)p4[2] + (float)p5[2]) + ((float)p6[2] + (float)p7[2]));
        a[3] += (((float)p0[3] + (float)p1[3]) + ((float)p2[3] + (float)p3[3]))
              + (((float)p4[3] + (float)p5[3]) + ((float)p6[3] + (float)p7[3]));
    }
    for (; i + 4 <= e; i += 4) {
        int u0 = col[i], u1 = col[i + 1], u2 = col[i + 2], u3 = col[i + 3];
        f16x4 p0 = ((const f16x4*)(xs + (size_t)u0 * 64))[l];
        f16x4 p1 = ((const f16x4*)(xs + (size_t)u1 * 64))[l];
        f16x4 p2 = ((const f16x4*)(xs + (size_t)u2 * 64))[l];
        f16x4 p3 = ((const f16x4*)(xs + (size_t)u3 * 64))[l];
        a[0] += ((float)p0[0] + (float)p1[0]) + ((float)p2[0] + (float)p3[0]);
        a[1] += ((float)p0[1] + (float)p1[1]) + ((float)p2[1] + (float)p3[1]);
        a[2] += ((float)p0[2] + (float)p1[2]) + ((float)p2[2] + (float)p3[2]);
        a[3] += ((float)p0[3] + (float)p1[3]) + ((float)p2[3] + (float)p3[3]);
    }
    for (; i < e; ++i) {
        f16x4 p = ((const f16x4*)(xs + (size_t)col[i] * 64))[l];
        a[0] += (float)p[0]; a[1] += (float)p[1]; a[2] += (float)p[2]; a[3] += (float)p[3];
    }
}

// R27: fused agg64 + GEMM1. Block = 16 quarter-waves = 16 nodes = one MFMA
// tile. Gather (R25-exact) -> LDS[16][72] -> 4 waves x 1 ct-tile of
// relu(t@W1+b1)*dinv -> xs1. g=bid&1 parity kept. N%16==0 in practice but
// guarded anyway.
__global__ void agg_gemm1_kernel(const _Float16* __restrict__ xs, _Float16* __restrict__ out,
                                 const int* __restrict__ row_ptr, const int* __restrict__ col,
                                 const _Float16* __restrict__ pk, const float* __restrict__ b1,
                                 const float* __restrict__ dinv, int N) {
    __shared__ _Float16 xl[16][72];
    int g = blockIdx.x & 1;
    int tile = blockIdx.x >> 1;
    int t = threadIdx.x;
    int qw = t >> 4, l = t & 15;
    int nv = tile * 16 + qw;
    int v0 = g * N + tile * 16;
    if (nv < N) {
        int v = g * N + nv;
        float a[4];
        gather_row4(xs, row_ptr, col, v, l, a);
        float dvv = dinv[v];
        f16x4 o = { (_Float16)(a[0] * dvv), (_Float16)(a[1] * dvv),
                    (_Float16)(a[2] * dvv), (_Float16)(a[3] * dvv) };
        *(f16x4*)&xl[qw][l * 4] = o;
    } else {
        f16x4 z = { (_Float16)0.f, (_Float16)0.f, (_Float16)0.f, (_Float16)0.f };
        *(f16x4*)&xl[qw][l * 4] = z;
    }
    __syncthreads();
    int ct = t >> 6;                       // wave id = column tile
    int lane = t & 63;
    int l15 = lane & 15, q = lane >> 4;
    const f16x8* arow = (const f16x8*)&xl[l15][0];
    f16x8 a0 = arow[q];
    f16x8 a1 = arow[q + 4];
    const f16x8* bp = (const f16x8*)pk;
    f32x4 c = {0.f, 0.f, 0.f, 0.f};
    c = __builtin_amdgcn_mfma_f32_16x16x32_f16(a0, bp[(ct * 2 + 0) * 64 + lane], c, 0, 0, 0);
    c = __builtin_amdgcn_mfma_f32_16x16x32_f16(a1, bp[(ct * 2 + 1) * 64 + lane], c, 0, 0, 0);
    float bj = b1[ct * 16 + l15];
    #pragma unroll
    for (int r = 0; r < 4; ++r) {
        int nr = tile * 16 + q * 4 + r;
        if (nr < N) {
            int vr = v0 + q * 4 + r;
            out[(size_t)vr * 64 + ct * 16 + l15] =
                (_Float16)(fmaxf(c[r] + bj, 0.f) * dinv[vr]);
        }
    }
}

// R27: fused agg64 + GEMM2+GEMM3. Gather -> LDS -> relu(t@W2+b2) -> LDS2
// -> (@W3)*dinv -> h3s. Waves 0..3 do W2's 4 ct-tiles; waves 0,1 do W3's 2.
__global__ void agg_gemm2_kernel(const _Float16* __restrict__ xs, _Float16* __restrict__ out,
                                 const int* __restrict__ row_ptr, const int* __restrict__ col,
                                 const _Float16* __restrict__ pk2, const _Float16* __restrict__ pk3,
                                 const float* __restrict__ b2, const float* __restrict__ dinv,
                                 int N) {
    __shared__ _Float16 xl[16][72];
    __shared__ _Float16 x2[16][72];
    int g = blockIdx.x & 1;
    int tile = blockIdx.x >> 1;
    int t = threadIdx.x;
    int qw = t >> 4, l = t & 15;
    int nv = tile * 16 + qw;
    int v0 = g * N + tile * 16;
    if (nv < N) {
        int v = g * N + nv;
        float a[4];
        gather_row4(xs, row_ptr, col, v, l, a);
        float dvv = dinv[v];
        f16x4 o = { (_Float16)(a[0] * dvv), (_Float16)(a[1] * dvv),
                    (_Float16)(a[2] * dvv), (_Float16)(a[3] * dvv) };
        *(f16x4*)&xl[qw][l * 4] = o;
    } else {
        f16x4 z = { (_Float16)0.f, (_Float16)0.f, (_Float16)0.f, (_Float16)0.f };
        *(f16x4*)&xl[qw][l * 4] = z;
    }
    __syncthreads();
    int ct = t >> 6;
    int lane = t & 63;
    int l15 = lane & 15, q = lane >> 4;
    {
        const f16x8* arow = (const f16x8*)&xl[l15][0];
        f16x8 a0 = arow[q];
        f16x8 a1 = arow[q + 4];
        const f16x8* bp2 = (const f16x8*)pk2;
        f32x4 c = {0.f, 0.f, 0.f, 0.f};
        c = __builtin_amdgcn_mfma_f32_16x16x32_f16(a0, bp2[(ct * 2 + 0) * 64 + lane], c, 0, 0, 0);
        c = __builtin_amdgcn_mfma_f32_16x16x32_f16(a1, bp2[(ct * 2 + 1) * 64 + lane], c, 0, 0, 0);
        float bj = b2[ct * 16 + l15];
        #pragma unroll
        for (int r = 0; r < 4; ++r)
            x2[q * 4 + r][ct * 16 + l15] = (_Float16)fmaxf(c[r] + bj, 0.f);
    }
    __syncthreads();
    if (ct < 2) {
        const f16x8* er = (const f16x8*)&x2[l15][0];
        f16x8 e0 = er[q];
        f16x8 e1 = er[q + 4];
        const f16x8* bp3 = (const f16x8*)pk3;
        f32x4 c = {0.f, 0.f, 0.f, 0.f};
        c = __builtin_amdgcn_mfma_f32_16x16x32_f16(e0, bp3[(ct * 2 + 0) * 64 + lane], c, 0, 0, 0);
        c = __builtin_amdgcn_mfma_f32_16x16x32_f16(e1, bp3[(ct * 2 + 1) * 64 + lane], c, 0, 0, 0);
        #pragma unroll
        for (int r = 0; r < 4; ++r) {
            int nr = tile * 16 + q * 4 + r;
            if (nr < N) {
                int vr = v0 + q * 4 + r;
                out[(size_t)vr * 32 + ct * 16 + l15] = (_Float16)(c[r] * dinv[vr]);
            }
        }
    }
}

// agg32: quarter-wave per node; a3 f32 out; fused colsums.
// R17 parity split; HG=512 SETTLED (R14+R20: L2 queue-bound).
__global__ void agg32_colsum_kernel(const _Float16* __restrict__ hs, float* __restrict__ out,
                                    const int* __restrict__ row_ptr, const int* __restrict__ col,
                                    const float* __restrict__ dinv, const float* __restrict__ b,
                                    float* __restrict__ msum, int N, int halfgrid) {
    int g = blockIdx.x & 1;
    int bid = blockIdx.x >> 1;
    int t = threadIdx.x;
    int l = t & 15;
    int qw = (bid * blockDim.x + t) >> 4;
    int nqw = (halfgrid * blockDim.x) >> 4;
    float blx = b[2 * l], bly = b[2 * l + 1];
    float csx = 0.f, csy = 0.f;
    int base = g * N;
    for (int vv = qw; vv < N; vv += nqw) {
        int v = base + vv;
        f16x2 sv = ((const f16x2*)(hs + (size_t)v * 32))[l];
        float ax = (float)sv.x, ay = (float)sv.y;
        int s = row_ptr[v], e = row_ptr[v + 1];
        int i = s;
        for (; i + 8 <= e; i += 8) {
            int u0 = col[i],     u1 = col[i + 1], u2 = col[i + 2], u3 = col[i + 3];
            int u4 = col[i + 4], u5 = col[i + 5], u6 = col[i + 6], u7 = col[i + 7];
            f16x2 p0 = ((const f16x2*)(hs + (size_t)u0 * 32))[l];
            f16x2 p1 = ((const f16x2*)(hs + (size_t)u1 * 32))[l];
            f16x2 p2 = ((const f16x2*)(hs + (size_t)u2 * 32))[l];
            f16x2 p3 = ((const f16x2*)(hs + (size_t)u3 * 32))[l];
            f16x2 p4 = ((const f16x2*)(hs + (size_t)u4 * 32))[l];
            f16x2 p5 = ((const f16x2*)(hs + (size_t)u5 * 32))[l];
            f16x2 p6 = ((const f16x2*)(hs + (size_t)u6 * 32))[l];
            f16x2 p7 = ((const f16x2*)(hs + (size_t)u7 * 32))[l];
            ax += (((float)p0.x + (float)p1.x) + ((float)p2.x + (float)p3.x))
                + (((float)p4.x + (float)p5.x) + ((float)p6.x + (float)p7.x));
            ay += (((float)p0.y + (float)p1.y) + ((float)p2.y + (float)p3.y))
                + (((float)p4.y + (float)p5.y) + ((float)p6.y + (float)p7.y));
        }
        for (; i + 4 <= e; i += 4) {
            int u0 = col[i], u1 = col[i + 1], u2 = col[i + 2], u3 = col[i + 3];
            f16x2 p0 = ((const f16x2*)(hs + (size_t)u0 * 32))[l];
            f16x2 p1 = ((const f16x2*)(hs + (size_t)u1 * 32))[l];
            f16x2 p2 = ((const f16x2*)(hs + (size_t)u2 * 32))[l];
            f16x2 p3 = ((const f16x2*)(hs + (size_t)u3 * 32))[l];
            ax += ((float)p0.x + (float)p1.x) + ((float)p2.x + (float)p3.x);
            ay += ((float)p0.y + (float)p1.y) + ((float)p2.y + (float)p3.y);
        }
        for (; i < e; ++i) {
            f16x2 p = ((const f16x2*)(hs + (size_t)col[i] * 32))[l];
            ax += (float)p.x; ay += (float)p.y;
        }
        float dv = dinv[v];
        float ox = ax * dv + blx, oy = ay * dv + bly;
        *(float2*)(out + (size_t)v * 32 + 2 * l) = make_float2(ox, oy);
        csx += ox; csy += oy;
    }
    __shared__ float spx[256], spy[256];
    spx[t] = csx; spy[t] = csy;
    __syncthreads();
    if (t < 16) {
        float sx = 0.f, sy = 0.f;
        for (int w = 0; w < 16; ++w) { sx += spx[w * 16 + t]; sy += spy[w * 16 + t]; }
        atomicAdd(&msum[g * 32 + 2 * t], sx);
        atomicAdd(&msum[g * 32 + 2 * t + 1], sy);
    }
}

// pool with ctx recomputed per block (R25-exact).
__global__ void pool2_kernel(const float* __restrict__ a3, const float* __restrict__ msum,
                             const float* __restrict__ W_att, float* __restrict__ pooled,
                             int N, int halfgrid) {
    int g = (blockIdx.x >= halfgrid) ? 1 : 0;
    int bid = blockIdx.x - g * halfgrid;
    int t = threadIdx.x;
    int j = t & 31;
    float invN = 1.f / (float)N;
    float acc = 0.f;
    for (int i = 0; i < 32; ++i) acc += (msum[g * 32 + i] * invN) * W_att[i * 32 + j];
    float cj = tanhf(acc);
    int hw = (bid * blockDim.x + t) >> 5;
    int nhw = (halfgrid * blockDim.x) >> 5;
    const float* base = a3 + (size_t)g * N * 32;
    float local = 0.f;
    for (int n = hw; n < N; n += nhw) {
        float v = base[(size_t)n * 32 + j];
        float d = v * cj;
        #pragma unroll
        for (int off = 16; off; off >>= 1) d += __shfl_xor(d, off);
        float s = 1.f / (1.f + __expf(-d));
        local += s * v;
    }
    __shared__ float sp[256];
    sp[t] = local;
    __syncthreads();
    if (t < 32) {
        float s = 0.f;
        for (int w = 0; w < 8; ++w) s += sp[w * 32 + t];
        atomicAdd(&pooled[g * 32 + t], s);
    }
}

__global__ void ntn_kernel(const float* __restrict__ p1, const float* __restrict__ p2,
                           const float* __restrict__ W_tn, const float* __restrict__ W_block,
                           const float* __restrict__ b_tn, float* __restrict__ out) {
    int k = threadIdx.x;
    if (k >= 16) return;
    float sc = 0.f;
    for (int i = 0; i < 32; ++i) {
        float e1 = p1[i];
        for (int j = 0; j < 32; ++j) sc += e1 * W_tn[i * 512 + j * 16 + k] * p2[j];
    }
    float bl = 0.f;
    for (int j = 0; j < 32; ++j)
        bl += W_block[k * 64 + j] * p1[j] + W_block[k * 64 + 32 + j] * p2[j];
    float v = sc + bl + b_tn[k];
    out[k] = v > 0.f ? v : 0.f;
}

extern "C" void kernel_launch(void* const* d_in, const int* in_sizes, int n_in,
                              void* d_out, int out_size, void* d_ws, size_t ws_size,
                              hipStream_t stream) {
    const float* f1     = (const float*)d_in[0];
    const int*   ei1    = (const int*)  d_in[1];
    const float* f2     = (const float*)d_in[2];
    const int*   ei2    = (const int*)  d_in[3];
    const float* W1     = (const float*)d_in[4];
    const float* b1     = (const float*)d_in[5];
    const float* W2     = (const float*)d_in[6];
    const float* b2     = (const float*)d_in[7];
    const float* W3     = (const float*)d_in[8];
    const float* b3     = (const float*)d_in[9];
    const float* W_att  = (const float*)d_in[10];
    const float* W_tn   = (const float*)d_in[11];
    const float* W_blk  = (const float*)d_in[12];
    const float* b_tn   = (const float*)d_in[13];

    int N = in_sizes[0] / 64;
    int E = in_sizes[1] / 2;
    int M = 2 * N;
    int E2 = 2 * E;
    int nsb = 11;
    while ((NSLICE << nsb) < M) nsb++;

    char* ws = (char*)d_ws;
    size_t off = 0;
    auto alloc = [&](size_t bytes) -> void* {
        void* p = ws + off;
        off += (bytes + 511) & ~(size_t)511;
        return p;
    };
    _Float16*  xsA     = (_Float16*) alloc((size_t)M * 64 * sizeof(_Float16)); // xs0; h3s reuse
    _Float16*  xsB     = (_Float16*) alloc((size_t)M * 64 * sizeof(_Float16)); // xs1
    // a3 (f32, M*32) shares region with bkt (uint32, E2): bkt dies at fillC.
    size_t a3_bytes  = (size_t)M * 32 * sizeof(float);
    size_t bkt_bytes = (size_t)E2 * sizeof(unsigned);
    char*  region    = (char*)alloc(a3_bytes > bkt_bytes ? a3_bytes : bkt_bytes);
    float*    a3  = (float*)region;
    unsigned* bkt = (unsigned*)region;
    int*       col     = (int*)      alloc((size_t)E2 * sizeof(int));
    int*       row_ptr = (int*)      alloc((size_t)(M + 1) * sizeof(int));
    float*     dinv    = (float*)    alloc((size_t)M * sizeof(float));
    int*       gcnt    = (int*)      alloc((size_t)NSLICE * NBLK * sizeof(int));
    int*       sliceSt = (int*)      alloc((NSLICE + 1) * sizeof(int));
    _Float16*  pk      = (_Float16*) alloc(10240 * sizeof(_Float16));
    float*     smalls  = (float*)    alloc(256 * sizeof(float));
    float* msum   = smalls;
    float* pooled = smalls + 64;
    _Float16* pk1 = pk, *pk2 = pk + 4096, *pk3 = pk + 8192;

    hipMemsetAsync(smalls, 0, 256 * sizeof(float), stream);

    int chunk = (E2 + NBLK - 1) / NBLK;
    int lds_fused = ((1 << nsb) + 1024) * sizeof(int);

    // CSR build (packed-bkt — R23)
    bcount_kernel<<<NBLK, 256, 0, stream>>>(ei1, ei2, E, N, gcnt, chunk, nsb);
    bscan_kernel<<<1, 1024, 0, stream>>>(gcnt, sliceSt, row_ptr, M, E2);
    bwrite_kernel<<<NBLK, 256, 0, stream>>>(ei1, ei2, E, N, gcnt, bkt, chunk, nsb);
    fillC_fused_kernel<<<NSLICE, 1024, lds_fused, stream>>>(bkt, sliceSt, row_ptr, dinv, col, M, nsb);

    // Weight packing + pre-scaled f16 input table
    packW_kernel<<<40, 256, 0, stream>>>(W1, W2, W3, pk);
    int cvb = (M * 64 / 4 + 255) / 256;
    scale0_kernel<<<cvb, 256, 0, stream>>>(f1, f2, dinv, xsA, N * 64);

    // Fused GCN stack (R27): block = 16 nodes = one MFMA tile; parity kept.
    int nbg = 2 * ((N + 15) / 16);
    agg_gemm1_kernel<<<nbg, 256, 0, stream>>>(xsA, xsB, row_ptr, col, pk1, b1, dinv, N);      // xs1
    agg_gemm2_kernel<<<nbg, 256, 0, stream>>>(xsB, xsA, row_ptr, col, pk2, pk3, b2, dinv, N); // h3s

    const int HG = 512;   // SETTLED: R14 (thrash) + R20 (L2-fit) both regress at 1024
    agg32_colsum_kernel<<<2 * HG, 256, 0, stream>>>(xsA, a3, row_ptr, col, dinv, b3, msum, N, HG);

    pool2_kernel<<<2 * 256, 256, 0, stream>>>(a3, msum, W_att, pooled, N, 256);
    ntn_kernel<<<1, 64, 0, stream>>>(pooled, pooled + 32, W_tn, W_blk, b_tn, (float*)d_out);
}

// Round 14
// 312.715 us; speedup vs baseline: 1.1424x; 1.0177x over previous
//
#include <hip/hip_runtime.h>
#include <math.h>

// ---------------------------------------------------------------------------
// SimGNN forward on MI355X — R27 best (318.3 us) + CSR single-pass + pool2
// parity (R28).
// R27 WIN: agg64+GEMM fusion (agg_gemm1/2), 335.8 -> 318.3; gather operating
// point undisturbed (both rows < agg32's 51 us).
// R28: (a) bcount+bscan+bwrite -> bucket_fused: per-block LDS chunk counts,
// ONE global atomicAdd per (block,slice) to reserve (16K atomics on 64
// cursors — not R15's 1.6M scattered), pass-2 write into slice-chunked bkt
// (cap = avg + 45 sigma, clamped). fillC sums the 64 final cursors for
// sliceStart. Kills 2 dispatches + bcount's 6.4 MB read. (b) pool2 parity
// split (g=bid&1): a3 reads hit the same per-XCD L2 agg32 just wrote
// (3rd application of the R17/R22 mechanism).
// R25: gathers L2 request-rate bound (R20/R24/R25) — structure frozen.
// R23 WIN: packed-bkt uint32. R22 WIN: agg64 parity. R20: HG=512 SETTLED.
// R17 WIN: agg32 parity. R16 WIN: fused fillC. R15: global atomics dead.
// R26: last-block-flag construct banned (container failure).
// Pipeline: bucket_fused -> fillC_fused -> packW/scale0
//   -> agg_gemm1 -> agg_gemm2 -> agg32_colsum -> pool2 -> ntn
// ---------------------------------------------------------------------------

#define NSLICE 64
#define NBLK   256

typedef _Float16 f16x8 __attribute__((ext_vector_type(8)));
typedef _Float16 f16x4 __attribute__((ext_vector_type(4)));
typedef _Float16 f16x2 __attribute__((ext_vector_type(2)));
typedef float    f32x4 __attribute__((ext_vector_type(4)));

// ---- R28: single-pass bucket build. Pass 1: LDS per-slice counts of this
// block's chunk. Reserve: one global atomicAdd per slice. Pass 2: re-read
// chunk (L2-hot) and place packed words into slice-chunked bkt.
__global__ void bucket_fused_kernel(const int* __restrict__ ei1, const int* __restrict__ ei2,
                                    int E, int N, int* __restrict__ gslice,
                                    unsigned* __restrict__ bkt, int chunk, int nsb, int cap) {
    __shared__ int cnt[NSLICE];
    __shared__ int rbase[NSLICE];
    int t = threadIdx.x;
    if (t < NSLICE) cnt[t] = 0;
    __syncthreads();
    int E2 = 2 * E;
    int lo = blockIdx.x * chunk;
    int hi = lo + chunk; if (hi > E2) hi = E2;
    for (int i = lo + t; i < hi; i += blockDim.x) {
        int dst = (i < E) ? ei1[E + i] : (ei2[E + (i - E)] + N);
        atomicAdd(&cnt[dst >> nsb], 1);
    }
    __syncthreads();
    if (t < NSLICE) {
        int c = cnt[t];
        rbase[t] = c ? atomicAdd(&gslice[t], c) : 0;
        cnt[t] = 0;                        // reuse as intra-block cursor
    }
    __syncthreads();
    unsigned mask = (1u << nsb) - 1u;
    for (int i = lo + t; i < hi; i += blockDim.x) {
        int src, dst;
        if (i < E) { src = ei1[i];         dst = ei1[E + i]; }
        else       { src = ei2[i - E] + N; dst = ei2[E + (i - E)] + N; }
        int s = dst >> nsb;
        int p = rbase[s] + atomicAdd(&cnt[s], 1);
        if (p >= cap) p = cap - 1;         // overflow clamp (45-sigma slack; no fault)
        bkt[(size_t)s * cap + p] = ((unsigned)src << nsb) | ((unsigned)dst & mask);
    }
}

// ---- fillC_fused (R28): sliceStart derived from final gslice counts.
// Phase 1 LDS histogram -> phase 2 scan (row_ptr/dinv) -> phase 3 col place.
__global__ void fillC_fused_kernel(const unsigned* __restrict__ bkt,
                                   const int* __restrict__ gslice,
                                   int* __restrict__ row_ptr, float* __restrict__ dinv,
                                   int* __restrict__ col, int M, int nsb, int cap) {
    extern __shared__ int sm[];           // [nbins] hist/cursor + [1024] scan
    int nbins = 1 << nsb;
    unsigned mask = (unsigned)nbins - 1u;
    int* hist = sm;
    int* ssum = sm + nbins;
    __shared__ int gs[NSLICE];
    int slice = blockIdx.x;
    int lo = slice << nsb;
    int t = threadIdx.x;                  // blockDim.x == 1024
    if (t < NSLICE) gs[t] = gslice[t];
    for (int j = t; j < nbins; j += 1024) hist[j] = 0;
    __syncthreads();
    int sstart = 0;
    for (int k = 0; k < slice; ++k) sstart += gs[k];
    int scount = gs[slice];
    size_t sb = (size_t)slice * cap;
    // Phase 1: histogram over low bits
    for (int i = t; i < scount; i += 1024)
        atomicAdd(&hist[bkt[sb + i] & mask], 1);
    __syncthreads();
    // Phase 2: exclusive scan over nbins
    const int PER = nbins >> 10;
    int base = t * PER;
    int vals[4];
    int acc = 0;
    for (int k = 0; k < PER; ++k) { vals[k] = hist[base + k]; acc += vals[k]; }
    ssum[t] = acc;
    __syncthreads();
    for (int off = 1; off < 1024; off <<= 1) {
        int v = (t >= off) ? ssum[t - off] : 0;
        __syncthreads();
        ssum[t] += v;
        __syncthreads();
    }
    int run = sstart + ((t == 0) ? 0 : ssum[t - 1]);
    for (int k = 0; k < PER; ++k) {
        int idx = lo + base + k;
        if (idx < M) {
            row_ptr[idx] = run;
            dinv[idx] = rsqrtf((float)(vals[k] + 1));
        }
        hist[base + k] = run;             // becomes the global write cursor
        run += vals[k];
    }
    __syncthreads();
    if (slice == NSLICE - 1 && t == 0) row_ptr[M] = sstart + scount;  // = E2
    // Phase 3: place edges (src = high bits)
    for (int i = t; i < scount; i += 1024) {
        unsigned w = bkt[sb + i];
        int p = atomicAdd(&hist[w & mask], 1);
        col[p] = (int)(w >> nsb);
    }
}

// xs0[i] = f16(x0[i] * dinv[i/64]); 4 elements per thread.
__global__ void scale0_kernel(const float* __restrict__ f1, const float* __restrict__ f2,
                              const float* __restrict__ dinv, _Float16* __restrict__ xs,
                              int n /* = N*64 */) {
    int i4 = (blockIdx.x * blockDim.x + threadIdx.x) * 4;
    if (i4 >= 2 * n) return;
    const float* src = (i4 < n) ? (f1 + i4) : (f2 + (i4 - n));
    float dv = dinv[i4 >> 6];
    float4 v = *(const float4*)src;
    f16x4 o = { (_Float16)(v.x * dv), (_Float16)(v.y * dv),
                (_Float16)(v.z * dv), (_Float16)(v.w * dv) };
    *(f16x4*)(xs + i4) = o;
}

// Pack W1,W2 (64x64) and W3 (64x32) into MFMA B-fragment order, f16.
__global__ void packW_kernel(const float* __restrict__ W1, const float* __restrict__ W2,
                             const float* __restrict__ W3, _Float16* __restrict__ pk) {
    int t = blockIdx.x * blockDim.x + threadIdx.x;
    if (t < 8192) {
        const float* W = (t < 4096) ? W1 : W2;
        int idx = t & 4095;
        int j = idx & 7, slot = idx >> 3;
        int lane = slot & 63, s = (slot >> 6) & 1, ct = slot >> 7;
        int k = s * 32 + ((lane >> 4) << 3) + j;
        int n = ct * 16 + (lane & 15);
        pk[t] = (_Float16)W[k * 64 + n];
    } else if (t < 10240) {
        int idx = t - 8192;
        int j = idx & 7, slot = idx >> 3;
        int lane = slot & 63, s = (slot >> 6) & 1, ct = slot >> 7;
        int k = s * 32 + ((lane >> 4) << 3) + j;
        int n = ct * 16 + (lane & 15);
        pk[t] = (_Float16)W3[k * 32 + n];
    }
}

// Gather one node's 64-f16 row (f16x4 lane slice), R25-exact loop.
__device__ inline void gather_row4(const _Float16* __restrict__ xs,
                                   const int* __restrict__ row_ptr,
                                   const int* __restrict__ col,
                                   int v, int l, float a[4]) {
    const f16x4* row = (const f16x4*)(xs + (size_t)v * 64);
    f16x4 sv = row[l];
    a[0] = (float)sv[0]; a[1] = (float)sv[1]; a[2] = (float)sv[2]; a[3] = (float)sv[3];
    int s = row_ptr[v], e = row_ptr[v + 1];
    int i = s;
    for (; i + 8 <= e; i += 8) {
        int u0 = col[i],     u1 = col[i + 1], u2 = col[i + 2], u3 = col[i + 3];
        int u4 = col[i + 4], u5 = col[i + 5], u6 = col[i + 6], u7 = col[i + 7];
        f16x4 p0 = ((const f16x4*)(xs + (size_t)u0 * 64))[l];
        f16x4 p1 = ((const f16x4*)(xs + (size_t)u1 * 64))[l];
        f16x4 p2 = ((const f16x4*)(xs + (size_t)u2 * 64))[l];
        f16x4 p3 = ((const f16x4*)(xs + (size_t)u3 * 64))[l];
        f16x4 p4 = ((const f16x4*)(xs + (size_t)u4 * 64))[l];
        f16x4 p5 = ((const f16x4*)(xs + (size_t)u5 * 64))[l];
        f16x4 p6 = ((const f16x4*)(xs + (size_t)u6 * 64))[l];
        f16x4 p7 = ((const f16x4*)(xs + (size_t)u7 * 64))[l];
        a[0] += (((float)p0[0] + (float)p1[0]) + ((float)p2[0] + (float)p3[0]))
              + (((float)p4[0] + (float)p5[0]) + ((float)p6[0] + (float)p7[0]));
        a[1] += (((float)p0[1] + (float)p1[1]) + ((float)p2[1] + (float)p3[1]))
              + (((float)p4[1] + (float)p5[1]) + ((float)p6[1] + (float)p7[1]));
        a[2] += (((float)p0[2] + (float)p1[2]) + ((float)p2[2] + (float)p3[2]))
              + (((float)p4[2] + (float)p5[2]) + ((float)p6[2] + (float)p7[2]));
        a[3] += (((float)p0[3] + (float)p1[3]) + ((float)p2[3] + (float)p3[3]))
              + (((float)p4[3] + (float)p5[3]) + ((float)p6[3] + (float)p7[3]));
    }
    for (; i + 4 <= e; i += 4) {
        int u0 = col[i], u1 = col[i + 1], u2 = col[i + 2], u3 = col[i + 3];
        f16x4 p0 = ((const f16x4*)(xs + (size_t)u0 * 64))[l];
        f16x4 p1 = ((const f16x4*)(xs + (size_t)u1 * 64))[l];
        f16x4 p2 = ((const f16x4*)(xs + (size_t)u2 * 64))[l];
        f16x4 p3 = ((const f16x4*)(xs + (size_t)u3 * 64))[l];
        a[0] += ((float)p0[0] + (float)p1[0]) + ((float)p2[0] + (float)p3[0]);
        a[1] += ((float)p0[1] + (float)p1[1]) + ((float)p2[1] + (float)p3[1]);
        a[2] += ((float)p0[2] + (float)p1[2]) + ((float)p2[2] + (float)p3[2]);
        a[3] += ((float)p0[3] + (float)p1[3]) + ((float)p2[3] + (float)p3[3]);
    }
    for (; i < e; ++i) {
        f16x4 p = ((const f16x4*)(xs + (size_t)col[i] * 64))[l];
        a[0] += (float)p[0]; a[1] += (float)p[1]; a[2] += (float)p[2]; a[3] += (float)p[3];
    }
}

// R27: fused agg64 + GEMM1. Block = 16 quarter-waves = 16 nodes = one MFMA
// tile. Gather -> LDS[16][72] -> 4 waves x 1 ct-tile. g=bid&1 parity kept.
__global__ void agg_gemm1_kernel(const _Float16* __restrict__ xs, _Float16* __restrict__ out,
                                 const int* __restrict__ row_ptr, const int* __restrict__ col,
                                 const _Float16* __restrict__ pk, const float* __restrict__ b1,
                                 const float* __restrict__ dinv, int N) {
    __shared__ _Float16 xl[16][72];
    int g = blockIdx.x & 1;
    int tile = blockIdx.x >> 1;
    int t = threadIdx.x;
    int qw = t >> 4, l = t & 15;
    int nv = tile * 16 + qw;
    int v0 = g * N + tile * 16;
    if (nv < N) {
        int v = g * N + nv;
        float a[4];
        gather_row4(xs, row_ptr, col, v, l, a);
        float dvv = dinv[v];
        f16x4 o = { (_Float16)(a[0] * dvv), (_Float16)(a[1] * dvv),
                    (_Float16)(a[2] * dvv), (_Float16)(a[3] * dvv) };
        *(f16x4*)&xl[qw][l * 4] = o;
    } else {
        f16x4 z = { (_Float16)0.f, (_Float16)0.f, (_Float16)0.f, (_Float16)0.f };
        *(f16x4*)&xl[qw][l * 4] = z;
    }
    __syncthreads();
    int ct = t >> 6;                       // wave id = column tile
    int lane = t & 63;
    int l15 = lane & 15, q = lane >> 4;
    const f16x8* arow = (const f16x8*)&xl[l15][0];
    f16x8 a0 = arow[q];
    f16x8 a1 = arow[q + 4];
    const f16x8* bp = (const f16x8*)pk;
    f32x4 c = {0.f, 0.f, 0.f, 0.f};
    c = __builtin_amdgcn_mfma_f32_16x16x32_f16(a0, bp[(ct * 2 + 0) * 64 + lane], c, 0, 0, 0);
    c = __builtin_amdgcn_mfma_f32_16x16x32_f16(a1, bp[(ct * 2 + 1) * 64 + lane], c, 0, 0, 0);
    float bj = b1[ct * 16 + l15];
    #pragma unroll
    for (int r = 0; r < 4; ++r) {
        int nr = tile * 16 + q * 4 + r;
        if (nr < N) {
            int vr = v0 + q * 4 + r;
            out[(size_t)vr * 64 + ct * 16 + l15] =
                (_Float16)(fmaxf(c[r] + bj, 0.f) * dinv[vr]);
        }
    }
}

// R27: fused agg64 + GEMM2+GEMM3. Gather -> LDS -> relu(t@W2+b2) -> LDS2
// -> (@W3)*dinv -> h3s.
__global__ void agg_gemm2_kernel(const _Float16* __restrict__ xs, _Float16* __restrict__ out,
                                 const int* __restrict__ row_ptr, const int* __restrict__ col,
                                 const _Float16* __restrict__ pk2, const _Float16* __restrict__ pk3,
                                 const float* __restrict__ b2, const float* __restrict__ dinv,
                                 int N) {
    __shared__ _Float16 xl[16][72];
    __shared__ _Float16 x2[16][72];
    int g = blockIdx.x & 1;
    int tile = blockIdx.x >> 1;
    int t = threadIdx.x;
    int qw = t >> 4, l = t & 15;
    int nv = tile * 16 + qw;
    int v0 = g * N + tile * 16;
    if (nv < N) {
        int v = g * N + nv;
        float a[4];
        gather_row4(xs, row_ptr, col, v, l, a);
        float dvv = dinv[v];
        f16x4 o = { (_Float16)(a[0] * dvv), (_Float16)(a[1] * dvv),
                    (_Float16)(a[2] * dvv), (_Float16)(a[3] * dvv) };
        *(f16x4*)&xl[qw][l * 4] = o;
    } else {
        f16x4 z = { (_Float16)0.f, (_Float16)0.f, (_Float16)0.f, (_Float16)0.f };
        *(f16x4*)&xl[qw][l * 4] = z;
    }
    __syncthreads();
    int ct = t >> 6;
    int lane = t & 63;
    int l15 = lane & 15, q = lane >> 4;
    {
        const f16x8* arow = (const f16x8*)&xl[l15][0];
        f16x8 a0 = arow[q];
        f16x8 a1 = arow[q + 4];
        const f16x8* bp2 = (const f16x8*)pk2;
        f32x4 c = {0.f, 0.f, 0.f, 0.f};
        c = __builtin_amdgcn_mfma_f32_16x16x32_f16(a0, bp2[(ct * 2 + 0) * 64 + lane], c, 0, 0, 0);
        c = __builtin_amdgcn_mfma_f32_16x16x32_f16(a1, bp2[(ct * 2 + 1) * 64 + lane], c, 0, 0, 0);
        float bj = b2[ct * 16 + l15];
        #pragma unroll
        for (int r = 0; r < 4; ++r)
            x2[q * 4 + r][ct * 16 + l15] = (_Float16)fmaxf(c[r] + bj, 0.f);
    }
    __syncthreads();
    if (ct < 2) {
        const f16x8* er = (const f16x8*)&x2[l15][0];
        f16x8 e0 = er[q];
        f16x8 e1 = er[q + 4];
        const f16x8* bp3 = (const f16x8*)pk3;
        f32x4 c = {0.f, 0.f, 0.f, 0.f};
        c = __builtin_amdgcn_mfma_f32_16x16x32_f16(e0, bp3[(ct * 2 + 0) * 64 + lane], c, 0, 0, 0);
        c = __builtin_amdgcn_mfma_f32_16x16x32_f16(e1, bp3[(ct * 2 + 1) * 64 + lane], c, 0, 0, 0);
        #pragma unroll
        for (int r = 0; r < 4; ++r) {
            int nr = tile * 16 + q * 4 + r;
            if (nr < N) {
                int vr = v0 + q * 4 + r;
                out[(size_t)vr * 32 + ct * 16 + l15] = (_Float16)(c[r] * dinv[vr]);
            }
        }
    }
}

// agg32: quarter-wave per node; a3 f32 out; fused colsums.
// R17 parity split; HG=512 SETTLED (R14+R20: L2 queue-bound).
__global__ void agg32_colsum_kernel(const _Float16* __restrict__ hs, float* __restrict__ out,
                                    const int* __restrict__ row_ptr, const int* __restrict__ col,
                                    const float* __restrict__ dinv, const float* __restrict__ b,
                                    float* __restrict__ msum, int N, int halfgrid) {
    int g = blockIdx.x & 1;
    int bid = blockIdx.x >> 1;
    int t = threadIdx.x;
    int l = t & 15;
    int qw = (bid * blockDim.x + t) >> 4;
    int nqw = (halfgrid * blockDim.x) >> 4;
    float blx = b[2 * l], bly = b[2 * l + 1];
    float csx = 0.f, csy = 0.f;
    int base = g * N;
    for (int vv = qw; vv < N; vv += nqw) {
        int v = base + vv;
        f16x2 sv = ((const f16x2*)(hs + (size_t)v * 32))[l];
        float ax = (float)sv.x, ay = (float)sv.y;
        int s = row_ptr[v], e = row_ptr[v + 1];
        int i = s;
        for (; i + 8 <= e; i += 8) {
            int u0 = col[i],     u1 = col[i + 1], u2 = col[i + 2], u3 = col[i + 3];
            int u4 = col[i + 4], u5 = col[i + 5], u6 = col[i + 6], u7 = col[i + 7];
            f16x2 p0 = ((const f16x2*)(hs + (size_t)u0 * 32))[l];
            f16x2 p1 = ((const f16x2*)(hs + (size_t)u1 * 32))[l];
            f16x2 p2 = ((const f16x2*)(hs + (size_t)u2 * 32))[l];
            f16x2 p3 = ((const f16x2*)(hs + (size_t)u3 * 32))[l];
            f16x2 p4 = ((const f16x2*)(hs + (size_t)u4 * 32))[l];
            f16x2 p5 = ((const f16x2*)(hs + (size_t)u5 * 32))[l];
            f16x2 p6 = ((const f16x2*)(hs + (size_t)u6 * 32))[l];
            f16x2 p7 = ((const f16x2*)(hs + (size_t)u7 * 32))[l];
            ax += (((float)p0.x + (float)p1.x) + ((float)p2.x + (float)p3.x))
                + (((float)p4.x + (float)p5.x) + ((float)p6.x + (float)p7.x));
            ay += (((float)p0.y + (float)p1.y) + ((float)p2.y + (float)p3.y))
                + (((float)p4.y + (float)p5.y) + ((float)p6.y + (float)p7.y));
        }
        for (; i + 4 <= e; i += 4) {
            int u0 = col[i], u1 = col[i + 1], u2 = col[i + 2], u3 = col[i + 3];
            f16x2 p0 = ((const f16x2*)(hs + (size_t)u0 * 32))[l];
            f16x2 p1 = ((const f16x2*)(hs + (size_t)u1 * 32))[l];
            f16x2 p2 = ((const f16x2*)(hs + (size_t)u2 * 32))[l];
            f16x2 p3 = ((const f16x2*)(hs + (size_t)u3 * 32))[l];
            ax += ((float)p0.x + (float)p1.x) + ((float)p2.x + (float)p3.x);
            ay += ((float)p0.y + (float)p1.y) + ((float)p2.y + (float)p3.y);
        }
        for (; i < e; ++i) {
            f16x2 p = ((const f16x2*)(hs + (size_t)col[i] * 32))[l];
            ax += (float)p.x; ay += (float)p.y;
        }
        float dv = dinv[v];
        float ox = ax * dv + blx, oy = ay * dv + bly;
        *(float2*)(out + (size_t)v * 32 + 2 * l) = make_float2(ox, oy);
        csx += ox; csy += oy;
    }
    __shared__ float spx[256], spy[256];
    spx[t] = csx; spy[t] = csy;
    __syncthreads();
    if (t < 16) {
        float sx = 0.f, sy = 0.f;
        for (int w = 0; w < 16; ++w) { sx += spx[w * 16 + t]; sy += spy[w * 16 + t]; }
        atomicAdd(&msum[g * 32 + 2 * t], sx);
        atomicAdd(&msum[g * 32 + 2 * t + 1], sy);
    }
}

// pool with ctx recomputed per block. R28: parity split (g=bid&1) so a3
// reads hit the per-XCD L2 that agg32 (same parity mapping) just wrote.
__global__ void pool2_kernel(const float* __restrict__ a3, const float* __restrict__ msum,
                             const float* __restrict__ W_att, float* __restrict__ pooled,
                             int N, int halfgrid) {
    int g = blockIdx.x & 1;
    int bid = blockIdx.x >> 1;
    int t = threadIdx.x;
    int j = t & 31;
    float invN = 1.f / (float)N;
    float acc = 0.f;
    for (int i = 0; i < 32; ++i) acc += (msum[g * 32 + i] * invN) * W_att[i * 32 + j];
    float cj = tanhf(acc);
    int hw = (bid * blockDim.x + t) >> 5;
    int nhw = (halfgrid * blockDim.x) >> 5;
    const float* base = a3 + (size_t)g * N * 32;
    float local = 0.f;
    for (int n = hw; n < N; n += nhw) {
        float v = base[(size_t)n * 32 + j];
        float d = v * cj;
        #pragma unroll
        for (int off = 16; off; off >>= 1) d += __shfl_xor(d, off);
        float s = 1.f / (1.f + __expf(-d));
        local += s * v;
    }
    __shared__ float sp[256];
    sp[t] = local;
    __syncthreads();
    if (t < 32) {
        float s = 0.f;
        for (int w = 0; w < 8; ++w) s += sp[w * 32 + t];
        atomicAdd(&pooled[g * 32 + t], s);
    }
}

__global__ void ntn_kernel(const float* __restrict__ p1, const float* __restrict__ p2,
                           const float* __restrict__ W_tn, const float* __restrict__ W_block,
                           const float* __restrict__ b_tn, float* __restrict__ out) {
    int k = threadIdx.x;
    if (k >= 16) return;
    float sc = 0.f;
    for (int i = 0; i < 32; ++i) {
        float e1 = p1[i];
        for (int j = 0; j < 32; ++j) sc += e1 * W_tn[i * 512 + j * 16 + k] * p2[j];
    }
    float bl = 0.f;
    for (int j = 0; j < 32; ++j)
        bl += W_block[k * 64 + j] * p1[j] + W_block[k * 64 + 32 + j] * p2[j];
    float v = sc + bl + b_tn[k];
    out[k] = v > 0.f ? v : 0.f;
}

extern "C" void kernel_launch(void* const* d_in, const int* in_sizes, int n_in,
                              void* d_out, int out_size, void* d_ws, size_t ws_size,
                              hipStream_t stream) {
    const float* f1     = (const float*)d_in[0];
    const int*   ei1    = (const int*)  d_in[1];
    const float* f2     = (const float*)d_in[2];
    const int*   ei2    = (const int*)  d_in[3];
    const float* W1     = (const float*)d_in[4];
    const float* b1     = (const float*)d_in[5];
    const float* W2     = (const float*)d_in[6];
    const float* b2     = (const float*)d_in[7];
    const float* W3     = (const float*)d_in[8];
    const float* b3     = (const float*)d_in[9];
    const float* W_att  = (const float*)d_in[10];
    const float* W_tn   = (const float*)d_in[11];
    const float* W_blk  = (const float*)d_in[12];
    const float* b_tn   = (const float*)d_in[13];

    int N = in_sizes[0] / 64;
    int E = in_sizes[1] / 2;
    int M = 2 * N;
    int E2 = 2 * E;
    int nsb = 11;
    while ((NSLICE << nsb) < M) nsb++;
    int cap = E2 / NSLICE + E2 / (4 * NSLICE) + 1024;   // avg + 25% + 1K slack

    char* ws = (char*)d_ws;
    size_t off = 0;
    auto alloc = [&](size_t bytes) -> void* {
        void* p = ws + off;
        off += (bytes + 511) & ~(size_t)511;
        return p;
    };
    _Float16*  xsA     = (_Float16*) alloc((size_t)M * 64 * sizeof(_Float16)); // xs0; h3s reuse
    _Float16*  xsB     = (_Float16*) alloc((size_t)M * 64 * sizeof(_Float16)); // xs1
    // a3 (f32, M*32) shares region with bkt (uint32, NSLICE*cap): bkt dies at fillC.
    size_t a3_bytes  = (size_t)M * 32 * sizeof(float);
    size_t bkt_bytes = (size_t)NSLICE * cap * sizeof(unsigned);
    char*  region    = (char*)alloc(a3_bytes > bkt_bytes ? a3_bytes : bkt_bytes);
    float*    a3  = (float*)region;
    unsigned* bkt = (unsigned*)region;
    int*       col     = (int*)      alloc((size_t)E2 * sizeof(int));
    int*       row_ptr = (int*)      alloc((size_t)(M + 1) * sizeof(int));
    float*     dinv    = (float*)    alloc((size_t)M * sizeof(float));
    int*       gslice  = (int*)      alloc(NSLICE * sizeof(int));
    _Float16*  pk      = (_Float16*) alloc(10240 * sizeof(_Float16));
    float*     smalls  = (float*)    alloc(256 * sizeof(float));
    float* msum   = smalls;
    float* pooled = smalls + 64;
    _Float16* pk1 = pk, *pk2 = pk + 4096, *pk3 = pk + 8192;

    hipMemsetAsync(smalls, 0, 256 * sizeof(float), stream);
    hipMemsetAsync(gslice, 0, NSLICE * sizeof(int), stream);

    int chunk = (E2 + NBLK - 1) / NBLK;
    int lds_fused = ((1 << nsb) + 1024) * sizeof(int);

    // CSR build (R28: single-pass chunk-reservation + fused fillC)
    bucket_fused_kernel<<<NBLK, 256, 0, stream>>>(ei1, ei2, E, N, gslice, bkt, chunk, nsb, cap);
    fillC_fused_kernel<<<NSLICE, 1024, lds_fused, stream>>>(bkt, gslice, row_ptr, dinv, col, M, nsb, cap);

    // Weight packing + pre-scaled f16 input table
    packW_kernel<<<40, 256, 0, stream>>>(W1, W2, W3, pk);
    int cvb = (M * 64 / 4 + 255) / 256;
    scale0_kernel<<<cvb, 256, 0, stream>>>(f1, f2, dinv, xsA, N * 64);

    // Fused GCN stack (R27): block = 16 nodes = one MFMA tile; parity kept.
    int nbg = 2 * ((N + 15) / 16);
    agg_gemm1_kernel<<<nbg, 256, 0, stream>>>(xsA, xsB, row_ptr, col, pk1, b1, dinv, N);      // xs1
    agg_gemm2_kernel<<<nbg, 256, 0, stream>>>(xsB, xsA, row_ptr, col, pk2, pk3, b2, dinv, N); // h3s

    const int HG = 512;   // SETTLED: R14 (thrash) + R20 (L2-fit) both regress at 1024
    agg32_colsum_kernel<<<2 * HG, 256, 0, stream>>>(xsA, a3, row_ptr, col, dinv, b3, msum, N, HG);

    pool2_kernel<<<2 * 256, 256, 0, stream>>>(a3, msum, W_att, pooled, N, 256);
    ntn_kernel<<<1, 64, 0, stream>>>(pooled, pooled + 32, W_tn, W_blk, b_tn, (float*)d_out);
}

// Round 15
// 299.726 us; speedup vs baseline: 1.1919x; 1.0433x over previous
//
#include <hip/hip_runtime.h>
#include <math.h>

// ---------------------------------------------------------------------------
// SimGNN forward on MI355X — R28 best (312.7 us) + NSLICE 64->256 (R29).
// R28 WIN: single-pass bucket (chunk-reservation) + pool2 parity, 318.3 ->
// 312.7. NOTE: absmax 32768 -> 262144 (passed; intra-row col-order rounding
// from chunk-reservation). Watch-item: revert reservation first on any
// future correctness failure.
// R29: fillC was 64 blocks x 1024 = 25% of CUs, ~25K edges/block serial.
// NSLICE=256 (nsb=9, nbins=512): fillC 256 blocks x 512 threads = full
// chip, 4x less work per block. bucket_fused LDS arrays 256-wide
// (reservation: 65K atomics on 256 counters — fine). cap=avg+25%+1K.
// Slices are CSR-build-only; agg/mfma kernels untouched.
// R27 WIN: agg64+GEMM fusion. R25: gathers L2 request-rate bound
// (R20/R24/R25) — structure frozen. R23 WIN: packed-bkt. R22 WIN: agg64
// parity. R20: HG=512 SETTLED. R17 WIN: agg32 parity. R26: last-block-flag
// banned (container failure).
// Pipeline: bucket_fused -> fillC_fused -> packW/scale0
//   -> agg_gemm1 -> agg_gemm2 -> agg32_colsum -> pool2 -> ntn
// ---------------------------------------------------------------------------

#define NSLICE 256
#define NBLK   256
#define FILLC_T 512

typedef _Float16 f16x8 __attribute__((ext_vector_type(8)));
typedef _Float16 f16x4 __attribute__((ext_vector_type(4)));
typedef _Float16 f16x2 __attribute__((ext_vector_type(2)));
typedef float    f32x4 __attribute__((ext_vector_type(4)));

// ---- R28/R29: single-pass bucket build. Pass 1: LDS per-slice counts of
// this block's chunk. Reserve: one global atomicAdd per (block,slice).
// Pass 2: re-read chunk (L2-hot), place packed words into slice-chunked bkt.
__global__ void bucket_fused_kernel(const int* __restrict__ ei1, const int* __restrict__ ei2,
                                    int E, int N, int* __restrict__ gslice,
                                    unsigned* __restrict__ bkt, int chunk, int nsb, int cap) {
    __shared__ int cnt[NSLICE];
    __shared__ int rbase[NSLICE];
    int t = threadIdx.x;                   // blockDim.x == 256 == NSLICE
    if (t < NSLICE) cnt[t] = 0;
    __syncthreads();
    int E2 = 2 * E;
    int lo = blockIdx.x * chunk;
    int hi = lo + chunk; if (hi > E2) hi = E2;
    for (int i = lo + t; i < hi; i += blockDim.x) {
        int dst = (i < E) ? ei1[E + i] : (ei2[E + (i - E)] + N);
        atomicAdd(&cnt[dst >> nsb], 1);
    }
    __syncthreads();
    if (t < NSLICE) {
        int c = cnt[t];
        rbase[t] = c ? atomicAdd(&gslice[t], c) : 0;
        cnt[t] = 0;                        // reuse as intra-block cursor
    }
    __syncthreads();
    unsigned mask = (1u << nsb) - 1u;
    for (int i = lo + t; i < hi; i += blockDim.x) {
        int src, dst;
        if (i < E) { src = ei1[i];         dst = ei1[E + i]; }
        else       { src = ei2[i - E] + N; dst = ei2[E + (i - E)] + N; }
        int s = dst >> nsb;
        int p = rbase[s] + atomicAdd(&cnt[s], 1);
        if (p >= cap) p = cap - 1;         // overflow clamp (no fault)
        bkt[(size_t)s * cap + p] = ((unsigned)src << nsb) | ((unsigned)dst & mask);
    }
}

// ---- fillC_fused (R29): 256 blocks x 512 threads. sliceStart from summing
// gslice. Phase 1 LDS histogram -> phase 2 scan (row_ptr/dinv) -> phase 3
// col placement. PER = nbins/512 (= 1 at nsb=9).
__global__ void fillC_fused_kernel(const unsigned* __restrict__ bkt,
                                   const int* __restrict__ gslice,
                                   int* __restrict__ row_ptr, float* __restrict__ dinv,
                                   int* __restrict__ col, int M, int nsb, int cap) {
    extern __shared__ int sm[];           // [nbins] hist/cursor + [512] scan
    int nbins = 1 << nsb;
    unsigned mask = (unsigned)nbins - 1u;
    int* hist = sm;
    int* ssum = sm + nbins;
    __shared__ int gs[NSLICE];
    int slice = blockIdx.x;
    int lo = slice << nsb;
    int t = threadIdx.x;                  // blockDim.x == FILLC_T
    for (int j = t; j < NSLICE; j += FILLC_T) gs[j] = gslice[j];
    for (int j = t; j < nbins; j += FILLC_T) hist[j] = 0;
    __syncthreads();
    int sstart = 0;
    for (int k = 0; k < slice; ++k) sstart += gs[k];
    int scount = gs[slice];
    size_t sb = (size_t)slice * cap;
    // Phase 1: histogram over low bits
    for (int i = t; i < scount; i += FILLC_T)
        atomicAdd(&hist[bkt[sb + i] & mask], 1);
    __syncthreads();
    // Phase 2: exclusive scan over nbins
    const int PER = nbins >> 9;           // nbins/512
    int base = t * PER;
    int vals[8];                          // supports nsb up to 12
    int acc = 0;
    for (int k = 0; k < PER; ++k) { vals[k] = hist[base + k]; acc += vals[k]; }
    ssum[t] = acc;
    __syncthreads();
    for (int off = 1; off < FILLC_T; off <<= 1) {
        int v = (t >= off) ? ssum[t - off] : 0;
        __syncthreads();
        ssum[t] += v;
        __syncthreads();
    }
    int run = sstart + ((t == 0) ? 0 : ssum[t - 1]);
    for (int k = 0; k < PER; ++k) {
        int idx = lo + base + k;
        if (idx < M) {
            row_ptr[idx] = run;
            dinv[idx] = rsqrtf((float)(vals[k] + 1));
        }
        hist[base + k] = run;             // becomes the global write cursor
        run += vals[k];
    }
    __syncthreads();
    if (slice == NSLICE - 1 && t == 0) row_ptr[M] = sstart + scount;  // = E2
    // Phase 3: place edges (src = high bits)
    for (int i = t; i < scount; i += FILLC_T) {
        unsigned w = bkt[sb + i];
        int p = atomicAdd(&hist[w & mask], 1);
        col[p] = (int)(w >> nsb);
    }
}

// xs0[i] = f16(x0[i] * dinv[i/64]); 4 elements per thread.
__global__ void scale0_kernel(const float* __restrict__ f1, const float* __restrict__ f2,
                              const float* __restrict__ dinv, _Float16* __restrict__ xs,
                              int n /* = N*64 */) {
    int i4 = (blockIdx.x * blockDim.x + threadIdx.x) * 4;
    if (i4 >= 2 * n) return;
    const float* src = (i4 < n) ? (f1 + i4) : (f2 + (i4 - n));
    float dv = dinv[i4 >> 6];
    float4 v = *(const float4*)src;
    f16x4 o = { (_Float16)(v.x * dv), (_Float16)(v.y * dv),
                (_Float16)(v.z * dv), (_Float16)(v.w * dv) };
    *(f16x4*)(xs + i4) = o;
}

// Pack W1,W2 (64x64) and W3 (64x32) into MFMA B-fragment order, f16.
__global__ void packW_kernel(const float* __restrict__ W1, const float* __restrict__ W2,
                             const float* __restrict__ W3, _Float16* __restrict__ pk) {
    int t = blockIdx.x * blockDim.x + threadIdx.x;
    if (t < 8192) {
        const float* W = (t < 4096) ? W1 : W2;
        int idx = t & 4095;
        int j = idx & 7, slot = idx >> 3;
        int lane = slot & 63, s = (slot >> 6) & 1, ct = slot >> 7;
        int k = s * 32 + ((lane >> 4) << 3) + j;
        int n = ct * 16 + (lane & 15);
        pk[t] = (_Float16)W[k * 64 + n];
    } else if (t < 10240) {
        int idx = t - 8192;
        int j = idx & 7, slot = idx >> 3;
        int lane = slot & 63, s = (slot >> 6) & 1, ct = slot >> 7;
        int k = s * 32 + ((lane >> 4) << 3) + j;
        int n = ct * 16 + (lane & 15);
        pk[t] = (_Float16)W3[k * 32 + n];
    }
}

// Gather one node's 64-f16 row (f16x4 lane slice), R25-exact loop.
__device__ inline void gather_row4(const _Float16* __restrict__ xs,
                                   const int* __restrict__ row_ptr,
                                   const int* __restrict__ col,
                                   int v, int l, float a[4]) {
    const f16x4* row = (const f16x4*)(xs + (size_t)v * 64);
    f16x4 sv = row[l];
    a[0] = (float)sv[0]; a[1] = (float)sv[1]; a[2] = (float)sv[2]; a[3] = (float)sv[3];
    int s = row_ptr[v], e = row_ptr[v + 1];
    int i = s;
    for (; i + 8 <= e; i += 8) {
        int u0 = col[i],     u1 = col[i + 1], u2 = col[i + 2], u3 = col[i + 3];
        int u4 = col[i + 4], u5 = col[i + 5], u6 = col[i + 6], u7 = col[i + 7];
        f16x4 p0 = ((const f16x4*)(xs + (size_t)u0 * 64))[l];
        f16x4 p1 = ((const f16x4*)(xs + (size_t)u1 * 64))[l];
        f16x4 p2 = ((const f16x4*)(xs + (size_t)u2 * 64))[l];
        f16x4 p3 = ((const f16x4*)(xs + (size_t)u3 * 64))[l];
        f16x4 p4 = ((const f16x4*)(xs + (size_t)u4 * 64))[l];
        f16x4 p5 = ((const f16x4*)(xs + (size_t)u5 * 64))[l];
        f16x4 p6 = ((const f16x4*)(xs + (size_t)u6 * 64))[l];
        f16x4 p7 = ((const f16x4*)(xs + (size_t)u7 * 64))[l];
        a[0] += (((float)p0[0] + (float)p1[0]) + ((float)p2[0] + (float)p3[0]))
              + (((float)p4[0] + (float)p5[0]) + ((float)p6[0] + (float)p7[0]));
        a[1] += (((float)p0[1] + (float)p1[1]) + ((float)p2[1] + (float)p3[1]))
              + (((float)p4[1] + (float)p5[1]) + ((float)p6[1] + (float)p7[1]));
        a[2] += (((float)p0[2] + (float)p1[2]) + ((float)p2[2] + (float)p3[2]))
              + (((float)p4[2] + (float)p5[2]) + ((float)p6[2] + (float)p7[2]));
        a[3] += (((float)p0[3] + (float)p1[3]) + ((float)p2[3] + (float)p3[3]))
              + (((float)p4[3] + (float)p5[3]) + ((float)p6[3] + (float)p7[3]));
    }
    for (; i + 4 <= e; i += 4) {
        int u0 = col[i], u1 = col[i + 1], u2 = col[i + 2], u3 = col[i + 3];
        f16x4 p0 = ((const f16x4*)(xs + (size_t)u0 * 64))[l];
        f16x4 p1 = ((const f16x4*)(xs + (size_t)u1 * 64))[l];
        f16x4 p2 = ((const f16x4*)(xs + (size_t)u2 * 64))[l];
        f16x4 p3 = ((const f16x4*)(xs + (size_t)u3 * 64))[l];
        a[0] += ((float)p0[0] + (float)p1[0]) + ((float)p2[0] + (float)p3[0]);
        a[1] += ((float)p0[1] + (float)p1[1]) + ((float)p2[1] + (float)p3[1]);
        a[2] += ((float)p0[2] + (float)p1[2]) + ((float)p2[2] + (float)p3[2]);
        a[3] += ((float)p0[3] + (float)p1[3]) + ((float)p2[3] + (float)p3[3]);
    }
    for (; i < e; ++i) {
        f16x4 p = ((const f16x4*)(xs + (size_t)col[i] * 64))[l];
        a[0] += (float)p[0]; a[1] += (float)p[1]; a[2] += (float)p[2]; a[3] += (float)p[3];
    }
}

// R27: fused agg64 + GEMM1. Block = 16 quarter-waves = 16 nodes = one MFMA
// tile. Gather -> LDS[16][72] -> 4 waves x 1 ct-tile. g=bid&1 parity kept.
__global__ void agg_gemm1_kernel(const _Float16* __restrict__ xs, _Float16* __restrict__ out,
                                 const int* __restrict__ row_ptr, const int* __restrict__ col,
                                 const _Float16* __restrict__ pk, const float* __restrict__ b1,
                                 const float* __restrict__ dinv, int N) {
    __shared__ _Float16 xl[16][72];
    int g = blockIdx.x & 1;
    int tile = blockIdx.x >> 1;
    int t = threadIdx.x;
    int qw = t >> 4, l = t & 15;
    int nv = tile * 16 + qw;
    int v0 = g * N + tile * 16;
    if (nv < N) {
        int v = g * N + nv;
        float a[4];
        gather_row4(xs, row_ptr, col, v, l, a);
        float dvv = dinv[v];
        f16x4 o = { (_Float16)(a[0] * dvv), (_Float16)(a[1] * dvv),
                    (_Float16)(a[2] * dvv), (_Float16)(a[3] * dvv) };
        *(f16x4*)&xl[qw][l * 4] = o;
    } else {
        f16x4 z = { (_Float16)0.f, (_Float16)0.f, (_Float16)0.f, (_Float16)0.f };
        *(f16x4*)&xl[qw][l * 4] = z;
    }
    __syncthreads();
    int ct = t >> 6;                       // wave id = column tile
    int lane = t & 63;
    int l15 = lane & 15, q = lane >> 4;
    const f16x8* arow = (const f16x8*)&xl[l15][0];
    f16x8 a0 = arow[q];
    f16x8 a1 = arow[q + 4];
    const f16x8* bp = (const f16x8*)pk;
    f32x4 c = {0.f, 0.f, 0.f, 0.f};
    c = __builtin_amdgcn_mfma_f32_16x16x32_f16(a0, bp[(ct * 2 + 0) * 64 + lane], c, 0, 0, 0);
    c = __builtin_amdgcn_mfma_f32_16x16x32_f16(a1, bp[(ct * 2 + 1) * 64 + lane], c, 0, 0, 0);
    float bj = b1[ct * 16 + l15];
    #pragma unroll
    for (int r = 0; r < 4; ++r) {
        int nr = tile * 16 + q * 4 + r;
        if (nr < N) {
            int vr = v0 + q * 4 + r;
            out[(size_t)vr * 64 + ct * 16 + l15] =
                (_Float16)(fmaxf(c[r] + bj, 0.f) * dinv[vr]);
        }
    }
}

// R27: fused agg64 + GEMM2+GEMM3. Gather -> LDS -> relu(t@W2+b2) -> LDS2
// -> (@W3)*dinv -> h3s.
__global__ void agg_gemm2_kernel(const _Float16* __restrict__ xs, _Float16* __restrict__ out,
                                 const int* __restrict__ row_ptr, const int* __restrict__ col,
                                 const _Float16* __restrict__ pk2, const _Float16* __restrict__ pk3,
                                 const float* __restrict__ b2, const float* __restrict__ dinv,
                                 int N) {
    __shared__ _Float16 xl[16][72];
    __shared__ _Float16 x2[16][72];
    int g = blockIdx.x & 1;
    int tile = blockIdx.x >> 1;
    int t = threadIdx.x;
    int qw = t >> 4, l = t & 15;
    int nv = tile * 16 + qw;
    int v0 = g * N + tile * 16;
    if (nv < N) {
        int v = g * N + nv;
        float a[4];
        gather_row4(xs, row_ptr, col, v, l, a);
        float dvv = dinv[v];
        f16x4 o = { (_Float16)(a[0] * dvv), (_Float16)(a[1] * dvv),
                    (_Float16)(a[2] * dvv), (_Float16)(a[3] * dvv) };
        *(f16x4*)&xl[qw][l * 4] = o;
    } else {
        f16x4 z = { (_Float16)0.f, (_Float16)0.f, (_Float16)0.f, (_Float16)0.f };
        *(f16x4*)&xl[qw][l * 4] = z;
    }
    __syncthreads();
    int ct = t >> 6;
    int lane = t & 63;
    int l15 = lane & 15, q = lane >> 4;
    {
        const f16x8* arow = (const f16x8*)&xl[l15][0];
        f16x8 a0 = arow[q];
        f16x8 a1 = arow[q + 4];
        const f16x8* bp2 = (const f16x8*)pk2;
        f32x4 c = {0.f, 0.f, 0.f, 0.f};
        c = __builtin_amdgcn_mfma_f32_16x16x32_f16(a0, bp2[(ct * 2 + 0) * 64 + lane], c, 0, 0, 0);
        c = __builtin_amdgcn_mfma_f32_16x16x32_f16(a1, bp2[(ct * 2 + 1) * 64 + lane], c, 0, 0, 0);
        float bj = b2[ct * 16 + l15];
        #pragma unroll
        for (int r = 0; r < 4; ++r)
            x2[q * 4 + r][ct * 16 + l15] = (_Float16)fmaxf(c[r] + bj, 0.f);
    }
    __syncthreads();
    if (ct < 2) {
        const f16x8* er = (const f16x8*)&x2[l15][0];
        f16x8 e0 = er[q];
        f16x8 e1 = er[q + 4];
        const f16x8* bp3 = (const f16x8*)pk3;
        f32x4 c = {0.f, 0.f, 0.f, 0.f};
        c = __builtin_amdgcn_mfma_f32_16x16x32_f16(e0, bp3[(ct * 2 + 0) * 64 + lane], c, 0, 0, 0);
        c = __builtin_amdgcn_mfma_f32_16x16x32_f16(e1, bp3[(ct * 2 + 1) * 64 + lane], c, 0, 0, 0);
        #pragma unroll
        for (int r = 0; r < 4; ++r) {
            int nr = tile * 16 + q * 4 + r;
            if (nr < N) {
                int vr = v0 + q * 4 + r;
                out[(size_t)vr * 32 + ct * 16 + l15] = (_Float16)(c[r] * dinv[vr]);
            }
        }
    }
}

// agg32: quarter-wave per node; a3 f32 out; fused colsums.
// R17 parity split; HG=512 SETTLED (R14+R20: L2 queue-bound).
__global__ void agg32_colsum_kernel(const _Float16* __restrict__ hs, float* __restrict__ out,
                                    const int* __restrict__ row_ptr, const int* __restrict__ col,
                                    const float* __restrict__ dinv, const float* __restrict__ b,
                                    float* __restrict__ msum, int N, int halfgrid) {
    int g = blockIdx.x & 1;
    int bid = blockIdx.x >> 1;
    int t = threadIdx.x;
    int l = t & 15;
    int qw = (bid * blockDim.x + t) >> 4;
    int nqw = (halfgrid * blockDim.x) >> 4;
    float blx = b[2 * l], bly = b[2 * l + 1];
    float csx = 0.f, csy = 0.f;
    int base = g * N;
    for (int vv = qw; vv < N; vv += nqw) {
        int v = base + vv;
        f16x2 sv = ((const f16x2*)(hs + (size_t)v * 32))[l];
        float ax = (float)sv.x, ay = (float)sv.y;
        int s = row_ptr[v], e = row_ptr[v + 1];
        int i = s;
        for (; i + 8 <= e; i += 8) {
            int u0 = col[i],     u1 = col[i + 1], u2 = col[i + 2], u3 = col[i + 3];
            int u4 = col[i + 4], u5 = col[i + 5], u6 = col[i + 6], u7 = col[i + 7];
            f16x2 p0 = ((const f16x2*)(hs + (size_t)u0 * 32))[l];
            f16x2 p1 = ((const f16x2*)(hs + (size_t)u1 * 32))[l];
            f16x2 p2 = ((const f16x2*)(hs + (size_t)u2 * 32))[l];
            f16x2 p3 = ((const f16x2*)(hs + (size_t)u3 * 32))[l];
            f16x2 p4 = ((const f16x2*)(hs + (size_t)u4 * 32))[l];
            f16x2 p5 = ((const f16x2*)(hs + (size_t)u5 * 32))[l];
            f16x2 p6 = ((const f16x2*)(hs + (size_t)u6 * 32))[l];
            f16x2 p7 = ((const f16x2*)(hs + (size_t)u7 * 32))[l];
            ax += (((float)p0.x + (float)p1.x) + ((float)p2.x + (float)p3.x))
                + (((float)p4.x + (float)p5.x) + ((float)p6.x + (float)p7.x));
            ay += (((float)p0.y + (float)p1.y) + ((float)p2.y + (float)p3.y))
                + (((float)p4.y + (float)p5.y) + ((float)p6.y + (float)p7.y));
        }
        for (; i + 4 <= e; i += 4) {
            int u0 = col[i], u1 = col[i + 1], u2 = col[i + 2], u3 = col[i + 3];
            f16x2 p0 = ((const f16x2*)(hs + (size_t)u0 * 32))[l];
            f16x2 p1 = ((const f16x2*)(hs + (size_t)u1 * 32))[l];
            f16x2 p2 = ((const f16x2*)(hs + (size_t)u2 * 32))[l];
            f16x2 p3 = ((const f16x2*)(hs + (size_t)u3 * 32))[l];
            ax += ((float)p0.x + (float)p1.x) + ((float)p2.x + (float)p3.x);
            ay += ((float)p0.y + (float)p1.y) + ((float)p2.y + (float)p3.y);
        }
        for (; i < e; ++i) {
            f16x2 p = ((const f16x2*)(hs + (size_t)col[i] * 32))[l];
            ax += (float)p.x; ay += (float)p.y;
        }
        float dv = dinv[v];
        float ox = ax * dv + blx, oy = ay * dv + bly;
        *(float2*)(out + (size_t)v * 32 + 2 * l) = make_float2(ox, oy);
        csx += ox; csy += oy;
    }
    __shared__ float spx[256], spy[256];
    spx[t] = csx; spy[t] = csy;
    __syncthreads();
    if (t < 16) {
        float sx = 0.f, sy = 0.f;
        for (int w = 0; w < 16; ++w) { sx += spx[w * 16 + t]; sy += spy[w * 16 + t]; }
        atomicAdd(&msum[g * 32 + 2 * t], sx);
        atomicAdd(&msum[g * 32 + 2 * t + 1], sy);
    }
}

// pool with ctx recomputed per block. R28 parity split (g=bid&1): a3 reads
// hit the per-XCD L2 agg32 (same parity mapping) just wrote.
__global__ void pool2_kernel(const float* __restrict__ a3, const float* __restrict__ msum,
                             const float* __restrict__ W_att, float* __restrict__ pooled,
                             int N, int halfgrid) {
    int g = blockIdx.x & 1;
    int bid = blockIdx.x >> 1;
    int t = threadIdx.x;
    int j = t & 31;
    float invN = 1.f / (float)N;
    float acc = 0.f;
    for (int i = 0; i < 32; ++i) acc += (msum[g * 32 + i] * invN) * W_att[i * 32 + j];
    float cj = tanhf(acc);
    int hw = (bid * blockDim.x + t) >> 5;
    int nhw = (halfgrid * blockDim.x) >> 5;
    const float* base = a3 + (size_t)g * N * 32;
    float local = 0.f;
    for (int n = hw; n < N; n += nhw) {
        float v = base[(size_t)n * 32 + j];
        float d = v * cj;
        #pragma unroll
        for (int off = 16; off; off >>= 1) d += __shfl_xor(d, off);
        float s = 1.f / (1.f + __expf(-d));
        local += s * v;
    }
    __shared__ float sp[256];
    sp[t] = local;
    __syncthreads();
    if (t < 32) {
        float s = 0.f;
        for (int w = 0; w < 8; ++w) s += sp[w * 32 + t];
        atomicAdd(&pooled[g * 32 + t], s);
    }
}

__global__ void ntn_kernel(const float* __restrict__ p1, const float* __restrict__ p2,
                           const float* __restrict__ W_tn, const float* __restrict__ W_block,
                           const float* __restrict__ b_tn, float* __restrict__ out) {
    int k = threadIdx.x;
    if (k >= 16) return;
    float sc = 0.f;
    for (int i = 0; i < 32; ++i) {
        float e1 = p1[i];
        for (int j = 0; j < 32; ++j) sc += e1 * W_tn[i * 512 + j * 16 + k] * p2[j];
    }
    float bl = 0.f;
    for (int j = 0; j < 32; ++j)
        bl += W_block[k * 64 + j] * p1[j] + W_block[k * 64 + 32 + j] * p2[j];
    float v = sc + bl + b_tn[k];
    out[k] = v > 0.f ? v : 0.f;
}

extern "C" void kernel_launch(void* const* d_in, const int* in_sizes, int n_in,
                              void* d_out, int out_size, void* d_ws, size_t ws_size,
                              hipStream_t stream) {
    const float* f1     = (const float*)d_in[0];
    const int*   ei1    = (const int*)  d_in[1];
    const float* f2     = (const float*)d_in[2];
    const int*   ei2    = (const int*)  d_in[3];
    const float* W1     = (const float*)d_in[4];
    const float* b1     = (const float*)d_in[5];
    const float* W2     = (const float*)d_in[6];
    const float* b2     = (const float*)d_in[7];
    const float* W3     = (const float*)d_in[8];
    const float* b3     = (const float*)d_in[9];
    const float* W_att  = (const float*)d_in[10];
    const float* W_tn   = (const float*)d_in[11];
    const float* W_blk  = (const float*)d_in[12];
    const float* b_tn   = (const float*)d_in[13];

    int N = in_sizes[0] / 64;
    int E = in_sizes[1] / 2;
    int M = 2 * N;
    int E2 = 2 * E;
    int nsb = 9;
    while ((NSLICE << nsb) < M) nsb++;
    int cap = E2 / NSLICE + E2 / (4 * NSLICE) + 1024;   // avg + 25% + 1K slack

    char* ws = (char*)d_ws;
    size_t off = 0;
    auto alloc = [&](size_t bytes) -> void* {
        void* p = ws + off;
        off += (bytes + 511) & ~(size_t)511;
        return p;
    };
    _Float16*  xsA     = (_Float16*) alloc((size_t)M * 64 * sizeof(_Float16)); // xs0; h3s reuse
    _Float16*  xsB     = (_Float16*) alloc((size_t)M * 64 * sizeof(_Float16)); // xs1
    // a3 (f32, M*32) shares region with bkt (uint32, NSLICE*cap): bkt dies at fillC.
    size_t a3_bytes  = (size_t)M * 32 * sizeof(float);
    size_t bkt_bytes = (size_t)NSLICE * cap * sizeof(unsigned);
    char*  region    = (char*)alloc(a3_bytes > bkt_bytes ? a3_bytes : bkt_bytes);
    float*    a3  = (float*)region;
    unsigned* bkt = (unsigned*)region;
    int*       col     = (int*)      alloc((size_t)E2 * sizeof(int));
    int*       row_ptr = (int*)      alloc((size_t)(M + 1) * sizeof(int));
    float*     dinv    = (float*)    alloc((size_t)M * sizeof(float));
    int*       gslice  = (int*)      alloc(NSLICE * sizeof(int));
    _Float16*  pk      = (_Float16*) alloc(10240 * sizeof(_Float16));
    float*     smalls  = (float*)    alloc(256 * sizeof(float));
    float* msum   = smalls;
    float* pooled = smalls + 64;
    _Float16* pk1 = pk, *pk2 = pk + 4096, *pk3 = pk + 8192;

    hipMemsetAsync(smalls, 0, 256 * sizeof(float), stream);
    hipMemsetAsync(gslice, 0, NSLICE * sizeof(int), stream);

    int chunk = (E2 + NBLK - 1) / NBLK;
    int lds_fused = ((1 << nsb) + FILLC_T) * sizeof(int);

    // CSR build (R29: 256 slices — fillC at full-chip occupancy)
    bucket_fused_kernel<<<NBLK, 256, 0, stream>>>(ei1, ei2, E, N, gslice, bkt, chunk, nsb, cap);
    fillC_fused_kernel<<<NSLICE, FILLC_T, lds_fused, stream>>>(bkt, gslice, row_ptr, dinv, col, M, nsb, cap);

    // Weight packing + pre-scaled f16 input table
    packW_kernel<<<40, 256, 0, stream>>>(W1, W2, W3, pk);
    int cvb = (M * 64 / 4 + 255) / 256;
    scale0_kernel<<<cvb, 256, 0, stream>>>(f1, f2, dinv, xsA, N * 64);

    // Fused GCN stack (R27): block = 16 nodes = one MFMA tile; parity kept.
    int nbg = 2 * ((N + 15) / 16);
    agg_gemm1_kernel<<<nbg, 256, 0, stream>>>(xsA, xsB, row_ptr, col, pk1, b1, dinv, N);      // xs1
    agg_gemm2_kernel<<<nbg, 256, 0, stream>>>(xsB, xsA, row_ptr, col, pk2, pk3, b2, dinv, N); // h3s

    const int HG = 512;   // SETTLED: R14 (thrash) + R20 (L2-fit) both regress at 1024
    agg32_colsum_kernel<<<2 * HG, 256, 0, stream>>>(xsA, a3, row_ptr, col, dinv, b3, msum, N, HG);

    pool2_kernel<<<2 * 256, 256, 0, stream>>>(a3, msum, W_att, pooled, N, 256);
    ntn_kernel<<<1, 64, 0, stream>>>(pooled, pooled + 32, W_tn, W_blk, b_tn, (float*)d_out);
}